// Round 7
// baseline (3609.477 us; speedup 1.0000x reference)
//
#include <hip/hip_runtime.h>

#define NTOKS 3152      // B*T*P = 2*8*197
#define DMODEL 384
#define EDIM 768
#define TWOE 1536
#define SDIM 16
#define RDIM 24
#define XDIM 56         // R + 2S
#define NLAYER 12
#define NPATCH 3136     // 16 * 196

typedef __attribute__((ext_vector_type(8))) short bf16x8;
typedef __attribute__((ext_vector_type(4))) float f32x4;

__device__ __forceinline__ float em_silu(float v) { return v / (1.f + __expf(-v)); }

__device__ __forceinline__ unsigned short f2bf(float f) {
  union { float f; unsigned int u; } v; v.f = f;
  const unsigned int r = v.u + 0x7fffu + ((v.u >> 16) & 1u);   // RTNE
  return (unsigned short)(r >> 16);
}
__device__ __forceinline__ unsigned int f2bf2(float lo, float hi) {
  return (unsigned int)f2bf(lo) | ((unsigned int)f2bf(hi) << 16);
}
__device__ __forceinline__ float bf2f(unsigned short s) {
  union { unsigned int u; float f; } v; v.u = (unsigned int)s << 16; return v.f;
}
__device__ __forceinline__ float bfbits_lo(unsigned int u) {
  union { unsigned int u; float f; } v; v.u = u << 16; return v.f;
}
__device__ __forceinline__ float bfbits_hi(unsigned int u) {
  union { unsigned int u; float f; } v; v.u = u & 0xffff0000u; return v.f;
}
__device__ __forceinline__ unsigned int addbf2(unsigned int a, unsigned int b) {
  return f2bf2(bfbits_lo(a) + bfbits_lo(b), bfbits_hi(a) + bfbits_hi(b));
}
__device__ __forceinline__ uint4 addbf8(uint4 a, uint4 b) {
  uint4 r;
  r.x = addbf2(a.x, b.x); r.y = addbf2(a.y, b.y);
  r.z = addbf2(a.z, b.z); r.w = addbf2(a.w, b.w);
  return r;
}
// fast softplus: max(a,0) + log(1+exp(-|a|)); native v_exp/v_log, abs err ~1e-6
__device__ __forceinline__ float em_softplus(float a) {
  const float t = __expf(-fabsf(a));
  return fmaxf(a, 0.f) + __logf(1.f + t);
}

// a[s] = q^(s+1) for s=0..15, log-depth product chain (depth 4, 18 muls)
__device__ __forceinline__ void pow_chain16(float q, float* a) {
  const float q2 = q * q, q4 = q2 * q2, q8 = q4 * q4;
  a[0] = q;       a[1] = q2;      a[2] = q2 * q;  a[3] = q4;
  a[4] = q4 * q;  a[5] = q4 * q2; a[6] = q4 * a[2]; a[7] = q8;
  a[8] = q8 * q;  a[9] = q8 * q2; a[10] = q8 * a[2]; a[11] = q8 * q4;
  a[12] = q8 * a[4]; a[13] = q8 * a[5]; a[14] = q8 * a[6]; a[15] = q8 * q8;
}

// ---------------- fp32 -> bf16 weight pre-conversion (n % 4 == 0) ----------------
__global__ __launch_bounds__(256)
void em_f2bf_arr(const float* __restrict__ s, unsigned short* __restrict__ d, size_t n) {
  const size_t i = ((size_t)blockIdx.x * 256 + threadIdx.x) * 4;
  if (i < n) {
    const float4 v = *reinterpret_cast<const float4*>(s + i);
    uint2 pk;
    pk.x = f2bf2(v.x, v.y); pk.y = f2bf2(v.z, v.w);
    *reinterpret_cast<uint2*>(d + i) = pk;
  }
}

// ---------------- im2col (bf16 out) for patch embed: col[3136][768] ----------------
__global__ __launch_bounds__(256)
void em_im2col(const float* __restrict__ x, unsigned short* __restrict__ col) {
  const int g = blockIdx.x * 256 + threadIdx.x;   // pr*768 + cc
  const int pr = g / 768;
  const int cc = g - pr * 768;
  const int np = pr % 196;
  const int bt = pr / 196;
  const int t = bt & 7, b = bt >> 3;
  const int hp = np / 14, wp = np - hp * 14;
  const int c = cc >> 8;
  const int rem = cc & 255;
  const int ph = rem >> 4, pw = rem & 15;
  col[g] = f2bf(x[(((size_t)(b * 3 + c) * 8 + t) * 224 + (hp * 16 + ph)) * 224 + (wp * 16 + pw)]);
}

// -------- patch embed epilogue fused with first residual+RMSNorm --------
__global__ __launch_bounds__(DMODEL)
void em_embed_norm(const float* __restrict__ tmpP, const float* __restrict__ pb,
                   const float* __restrict__ cls, const float* __restrict__ pos,
                   const float* __restrict__ w,
                   float* __restrict__ residual, unsigned short* __restrict__ xn_bf) {
  const int tok = blockIdx.x;
  const int d = threadIdx.x;
  const int p = tok % 197;
  const int bt = tok / 197;
  const int t = bt & 7;
  float v;
  if (p == 0) {
    v = cls[d] + pos[d];
  } else {
    const int np = p - 1;
    const float div = powf(10000.f, (float)(d & ~1) * (1.f / 384.f));
    const float ang = (float)t / div;
    const float enc = (d & 1) ? cosf(ang) : sinf(ang);
    v = tmpP[((size_t)bt * 196 + np) * DMODEL + d] + pb[d] + pos[(size_t)p * DMODEL + d] + enc;
  }
  const size_t idx = (size_t)tok * DMODEL + d;
  residual[idx] = v;
  float ss = v * v;
  #pragma unroll
  for (int off = 32; off; off >>= 1) ss += __shfl_xor(ss, off, 64);
  __shared__ float red[6];
  if ((d & 63) == 0) red[d >> 6] = ss;
  __syncthreads();
  float tot = 0.f;
  #pragma unroll
  for (int i = 0; i < 6; ++i) tot += red[i];
  const float scale = rsqrtf(tot * (1.f / 384.f) + 1e-5f);
  xn_bf[idx] = f2bf(v * scale * w[d]);
}

// ------- residual add (+ optional K-split partial) + RMSNorm; bf16 (layers) / fp32 (final) -----
__global__ __launch_bounds__(DMODEL)
void em_add_rmsnorm(const float* __restrict__ hidden, const float* __restrict__ hidden2,
                    const float* __restrict__ res_in,
                    float* __restrict__ res_out, const float* __restrict__ w,
                    float* __restrict__ out, unsigned short* __restrict__ out_bf) {
  const int tok = blockIdx.x;
  const int d = threadIdx.x;
  const size_t idx = (size_t)tok * DMODEL + d;
  float v = hidden[idx] + res_in[idx];
  if (hidden2) v += hidden2[idx];
  if (res_out) res_out[idx] = v;
  float ss = v * v;
  #pragma unroll
  for (int off = 32; off; off >>= 1) ss += __shfl_xor(ss, off, 64);
  __shared__ float red[6];
  if ((d & 63) == 0) red[d >> 6] = ss;
  __syncthreads();
  float tot = 0.f;
  #pragma unroll
  for (int i = 0; i < 6; ++i) tot += red[i];
  const float scale = rsqrtf(tot * (1.f / 384.f) + 1e-5f);
  const float r = v * scale * w[d];
  if (out_bf) out_bf[idx] = f2bf(r);
  else out[idx] = r;
}

// ====== MFMA GEMM, bf16 A (+A2) and bf16 W, LDS ping-pong double-buffer, optional K-split ======
// grid: (N/TN, ceil(M/TM), nks); K = per-slice length, KS = full row stride.
#define TM 128
#define TN 64
#define LDT 40   // ushorts per LDS row (32 + 8 pad)
__global__ __launch_bounds__(256)
void em_gemm_abf(const unsigned short* __restrict__ A, const unsigned short* __restrict__ A2,
                 const unsigned short* __restrict__ W, float* __restrict__ C,
                 int M, int N, int K, int KS) {
  __shared__ unsigned short As[2][TM * LDT];
  __shared__ unsigned short Bs[2][TN * LDT];
  const int tid = threadIdx.x;
  const int bm = blockIdx.y * TM;
  const int bn = blockIdx.x * TN;
  const int kk0 = blockIdx.z * K;
  const int kkend = kk0 + K;
  const int wave = tid >> 6, lane = tid & 63;
  const int wm = (wave >> 1) * 64, wn = (wave & 1) * 32;
  const int mq = lane & 15, quad = lane >> 4;
  f32x4 acc[4][2] = {};
  const int ar = tid >> 1;
  const int ah = (tid & 1) * 16;
  const int br = tid >> 2;
  const int bk = (tid & 3) * 8;
  const int arow = bm + ar;

  uint4 a0, a1, b0;
  auto load_tile = [&](int kk) {
    a0 = {0, 0, 0, 0}; a1 = {0, 0, 0, 0};
    if (arow < M) {
      const uint4* pa = reinterpret_cast<const uint4*>(A + (size_t)arow * KS + kk + ah);
      a0 = pa[0]; a1 = pa[1];
      if (A2) {
        const uint4* pb = reinterpret_cast<const uint4*>(A2 + (size_t)arow * KS + kk + ah);
        a0 = addbf8(a0, pb[0]); a1 = addbf8(a1, pb[1]);
      }
    }
    b0 = *reinterpret_cast<const uint4*>(W + (size_t)(bn + br) * KS + kk + bk);
  };
  auto store_tile = [&](int buf) {
    uint4* dst = reinterpret_cast<uint4*>(&As[buf][ar * LDT + ah]);
    dst[0] = a0; dst[1] = a1;
    *reinterpret_cast<uint4*>(&Bs[buf][br * LDT + bk]) = b0;
  };

  load_tile(kk0);
  store_tile(0);
  __syncthreads();
  int cur = 0;
  for (int kk = kk0; kk < kkend; kk += 32) {
    const bool have = (kk + 32) < kkend;
    if (have) load_tile(kk + 32);
    bf16x8 bfr[2];
    #pragma unroll
    for (int j = 0; j < 2; ++j)
      bfr[j] = *reinterpret_cast<const bf16x8*>(&Bs[cur][(wn + j * 16 + mq) * LDT + quad * 8]);
    #pragma unroll
    for (int i = 0; i < 4; ++i) {
      const bf16x8 afr = *reinterpret_cast<const bf16x8*>(&As[cur][(wm + i * 16 + mq) * LDT + quad * 8]);
      acc[i][0] = __builtin_amdgcn_mfma_f32_16x16x32_bf16(afr, bfr[0], acc[i][0], 0, 0, 0);
      acc[i][1] = __builtin_amdgcn_mfma_f32_16x16x32_bf16(afr, bfr[1], acc[i][1], 0, 0, 0);
    }
    if (have) {
      store_tile(cur ^ 1);
      __syncthreads();
      cur ^= 1;
    }
  }
  float* Cz = C + (size_t)blockIdx.z * M * N;
  #pragma unroll
  for (int i = 0; i < 4; ++i) {
    const int mbase = bm + wm + i * 16 + quad * 4;
    #pragma unroll
    for (int j = 0; j < 2; ++j) {
      const int col = bn + wn + j * 16 + mq;
      #pragma unroll
      for (int p = 0; p < 4; ++p) {
        const int m = mbase + p;
        if (m < M) Cz[(size_t)m * N + col] = acc[i][j][p];
      }
    }
  }
}

// ===== transposed xproj GEMM (bf16 W), K-split x2, LDS ping-pong double-buffer:
//       dblT[slice][64][NTOKS] = xp[56, Kslice] @ u[:, Kslice]^T ; consumers sum slices =====
// grid: (ceil(NTOKS/64), 2, dirs)
__global__ __launch_bounds__(256)
void em_gemm_xpT(const unsigned short* __restrict__ ubf, const unsigned short* __restrict__ ubr,
                 const unsigned short* __restrict__ xpf, const unsigned short* __restrict__ xpr,
                 float* __restrict__ dblTf, float* __restrict__ dblTr) {
  const int dir = blockIdx.z;
  const int ks = blockIdx.y;                // K slice: 0..1
  const unsigned short* U = dir ? ubr : ubf;
  const unsigned short* W = dir ? xpr : xpf;
  float* C = dir ? dblTr : dblTf;
  __shared__ unsigned short As[2][64 * LDT];   // xp tile (56 real rows)
  __shared__ unsigned short Bs[2][64 * LDT];   // u tile (64 tokens)
  const int tid = threadIdx.x;
  const int bn = blockIdx.x * 64;           // token base
  const int wave = tid >> 6, lane = tid & 63;
  const int wm = wave * 16;
  const int mq = lane & 15, quad = lane >> 4;
  f32x4 acc[4] = {};
  const int sr = tid >> 2;
  const int sq = (tid & 3) * 8;
  const int k0 = ks * (EDIM / 2), k1 = k0 + EDIM / 2;
  const int btok = bn + sr;

  uint4 wa, ub;
  auto load_tile = [&](int kk) {
    wa = {0, 0, 0, 0}; ub = {0, 0, 0, 0};
    if (sr < XDIM)
      wa = *reinterpret_cast<const uint4*>(W + (size_t)sr * EDIM + kk + sq);
    if (btok < NTOKS)
      ub = *reinterpret_cast<const uint4*>(U + (size_t)btok * EDIM + kk + sq);
  };
  auto store_tile = [&](int buf) {
    *reinterpret_cast<uint4*>(&As[buf][sr * LDT + sq]) = wa;
    *reinterpret_cast<uint4*>(&Bs[buf][sr * LDT + sq]) = ub;
  };

  load_tile(k0);
  store_tile(0);
  __syncthreads();
  int cur = 0;
  for (int kk = k0; kk < k1; kk += 32) {
    const bool have = (kk + 32) < k1;
    if (have) load_tile(kk + 32);
    const bf16x8 afr = *reinterpret_cast<const bf16x8*>(&As[cur][(wm + mq) * LDT + quad * 8]);
    #pragma unroll
    for (int j = 0; j < 4; ++j) {
      const bf16x8 bfr = *reinterpret_cast<const bf16x8*>(&Bs[cur][(j * 16 + mq) * LDT + quad * 8]);
      acc[j] = __builtin_amdgcn_mfma_f32_16x16x32_bf16(afr, bfr, acc[j], 0, 0, 0);
    }
    if (have) {
      store_tile(cur ^ 1);
      __syncthreads();
      cur ^= 1;
    }
  }
  #pragma unroll
  for (int j = 0; j < 4; ++j) {
    const int tok = bn + j * 16 + mq;
    if (tok < NTOKS) {
      #pragma unroll
      for (int p = 0; p < 4; ++p) {
        const int m = wm + quad * 4 + p;
        C[(size_t)(ks * 64 + m) * NTOKS + tok] = acc[j][p];
      }
    }
  }
}

// ---------------- dt projection: dt[tok][e] = softplus(r(tok)·dtw[e] + dtb[e]) ----------------
// grid: (EDIM/256, NTOKS/16, dirs)
#define DT_TT 16
__global__ __launch_bounds__(256)
void em_dtproj(const float* __restrict__ dblTf, const float* __restrict__ dblTr,
               const float* __restrict__ dtwf, const float* __restrict__ dtwr,
               const float* __restrict__ dtbf, const float* __restrict__ dtbr,
               float* __restrict__ dtf, float* __restrict__ dtr) {
  const int e = blockIdx.x * 256 + threadIdx.x;
  const int t0 = blockIdx.y * DT_TT;
  const int dir = blockIdx.z;
  const float* dblT = dir ? dblTr : dblTf;
  const float* dtw = dir ? dtwr : dtwf;
  const float* dtb = dir ? dtbr : dtbf;
  float* dto = dir ? dtr : dtf;
  __shared__ float r[DT_TT][RDIM + 1];   // +1 pad: odd stride, conflict-free
  for (int i = threadIdx.x; i < DT_TT * RDIM; i += 256) {   // 384 entries, 256 threads
    const int tt = i & (DT_TT - 1);
    const int j = i >> 4;
    const int tok = t0 + tt;                                // NTOKS % 16 == 0: always valid
    r[tt][j] = dblT[(size_t)j * NTOKS + tok] + dblT[(size_t)(64 + j) * NTOKS + tok];
  }
  __syncthreads();
  const float4* wp = reinterpret_cast<const float4*>(dtw + (size_t)e * RDIM);  // 96B aligned
  float w[RDIM];
  #pragma unroll
  for (int q = 0; q < 6; ++q) {
    const float4 v = wp[q];
    w[q * 4 + 0] = v.x; w[q * 4 + 1] = v.y; w[q * 4 + 2] = v.z; w[q * 4 + 3] = v.w;
  }
  const float b = dtb[e];
  float* o = dto + (size_t)t0 * EDIM + e;
  #pragma unroll 4
  for (int tt = 0; tt < DT_TT; ++tt) {
    float a = b;
    #pragma unroll
    for (int j = 0; j < RDIM; ++j) a += r[tt][j] * w[j];   // LDS broadcast reads
    o[(size_t)tt * EDIM] = em_softplus(a);
  }
}

// ---------------- depthwise conv + SiLU; sliding register window, 16 tokens/thread ------------
// grid: (EDIM/256, ceil(NTOKS/16), dirs)
#define CONV_CT 16
__global__ __launch_bounds__(256)
void em_conv_silu(const float* __restrict__ xz,
                  const float* __restrict__ cwf, const float* __restrict__ cbf,
                  const float* __restrict__ cwr, const float* __restrict__ cbr,
                  unsigned short* __restrict__ ubf, unsigned short* __restrict__ ubr, int L) {
  const int e = blockIdx.x * 256 + threadIdx.x;
  const int t0 = blockIdx.y * CONV_CT;
  const int dir = blockIdx.z;
  const float* cw = dir ? cwr : cwf;
  const float* cb = dir ? cbr : cbf;
  unsigned short* out = dir ? ubr : ubf;
  const float4 wv = *reinterpret_cast<const float4*>(cw + e * 4);
  const float w0 = wv.x, w1 = wv.y, w2 = wv.z, w3 = wv.w;
  const float bv = cb[e];
  const float* xcol = xz + e;               // u-half column of xz, stride TWOE per token
  int l = t0 % L;
  if (dir == 0) {
    float xm1 = (l >= 1) ? xcol[(size_t)(t0 - 1) * TWOE] : 0.f;
    float xm2 = (l >= 2) ? xcol[(size_t)(t0 - 2) * TWOE] : 0.f;
    float xm3 = (l >= 3) ? xcol[(size_t)(t0 - 3) * TWOE] : 0.f;
    for (int tt = 0; tt < CONV_CT; ++tt) {
      const int tok = t0 + tt;
      if (tok >= NTOKS) break;
      const float xc = xcol[(size_t)tok * TWOE];
      float acc = bv + xc * w3;
      if (l >= 1) acc += xm1 * w2;
      if (l >= 2) acc += xm2 * w1;
      if (l >= 3) acc += xm3 * w0;
      out[(size_t)tok * EDIM + e] = f2bf(em_silu(acc));
      xm3 = xm2; xm2 = xm1; xm1 = xc;
      if (++l == L) l = 0;                  // new sequence: guards zero stale window
    }
  } else {
    float xc  = xcol[(size_t)t0 * TWOE];
    float xp1 = (t0 + 1 < NTOKS) ? xcol[(size_t)(t0 + 1) * TWOE] : 0.f;
    float xp2 = (t0 + 2 < NTOKS) ? xcol[(size_t)(t0 + 2) * TWOE] : 0.f;
    for (int tt = 0; tt < CONV_CT; ++tt) {
      const int tok = t0 + tt;
      if (tok >= NTOKS) break;
      const float xp3 = (tok + 3 < NTOKS) ? xcol[(size_t)(tok + 3) * TWOE] : 0.f;
      float acc = bv + xc * w3;
      if (l + 1 < L) acc += xp1 * w2;
      if (l + 2 < L) acc += xp2 * w1;
      if (l + 3 < L) acc += xp3 * w0;
      out[(size_t)tok * EDIM + e] = f2bf(em_silu(acc));
      xc = xp1; xp1 = xp2; xp2 = xp3;
      if (++l == L) l = 0;
    }
  }
}

// ================= chunked scan (templated chunk length) =================
// PW path: A[s] == -(s+1) (verified at runtime) -> exp(dtv*A[s]) = q^(s+1), q=exp(-dtv).
// Chunk decay product stored COMPRESSED as dsum: P[s] = exp(A[s]*dsum) exactly, for any A.
template<int CL, bool PW>
__device__ __forceinline__ void scan_sum_core(
    const float* __restrict__ dt, const unsigned short* __restrict__ u,
    const float (* __restrict__ Bs)[SDIM], const float* __restrict__ A,
    float* __restrict__ h, float& dsum,
    int n, int L, int p0, int len, int dir, int e) {
  auto step = [&](int j) {
    const int pos = p0 + j;
    const int l = dir ? (L - 1 - pos) : pos;
    const size_t tok = (size_t)n * L + l;
    const float dtv = dt[tok * EDIM + e];
    const float dtu = dtv * bf2f(u[tok * EDIM + e]);
    dsum += dtv;
    float a[SDIM];
    if (PW) {
      pow_chain16(__expf(-dtv), a);
    } else {
      #pragma unroll
      for (int s = 0; s < SDIM; ++s) a[s] = __expf(dtv * A[s]);
    }
    const float4* b4 = reinterpret_cast<const float4*>(Bs[j]);
    float bb[SDIM];
    #pragma unroll
    for (int q = 0; q < 4; ++q) {
      const float4 v = b4[q];
      bb[4*q] = v.x; bb[4*q+1] = v.y; bb[4*q+2] = v.z; bb[4*q+3] = v.w;
    }
    #pragma unroll
    for (int s = 0; s < SDIM; ++s) h[s] = a[s] * h[s] + dtu * bb[s];
  };
  if (len == CL) {
    #pragma unroll
    for (int j = 0; j < CL; ++j) step(j);
  } else {
    for (int j = 0; j < len; ++j) step(j);
  }
}

template<int CL>
__global__ __launch_bounds__(256)
void em_scan_sum(const float* __restrict__ dtf, const float* __restrict__ dtr,
                 const unsigned short* __restrict__ ubf, const unsigned short* __restrict__ ubr,
                 const float* __restrict__ dblTf, const float* __restrict__ dblTr,
                 const float* __restrict__ Alogf, const float* __restrict__ Alogr,
                 float* __restrict__ Psf, float* __restrict__ Psr,
                 float* __restrict__ Hfw, float* __restrict__ Hrv,
                 int L, int nchunks) {
  const int dir = blockIdx.z;
  const int n = blockIdx.y / nchunks;
  const int c = blockIdx.y % nchunks;
  const int tid = threadIdx.x;
  const int e = blockIdx.x * 256 + tid;
  const float* dt = dir ? dtr : dtf;
  const unsigned short* u = dir ? ubr : ubf;
  const float* dblT = dir ? dblTr : dblTf;
  const float* Alog = dir ? Alogr : Alogf;
  float* Ps = dir ? Psr : Psf;
  float* H = dir ? Hrv : Hfw;
  const int p0 = c * CL;
  const int len = min(CL, L - p0);
  __shared__ __align__(16) float Bs[CL][SDIM];
  for (int i = tid; i < CL * SDIM; i += 256) {
    const int j = i % CL, s = i / CL;
    if (j < len) {
      const int pos = p0 + j;
      const int l = dir ? (L - 1 - pos) : pos;
      const size_t col = (size_t)n * L + l;
      Bs[j][s] = dblT[(size_t)(RDIM + s) * NTOKS + col]
               + dblT[(size_t)(64 + RDIM + s) * NTOKS + col];
    }
  }
  __syncthreads();
  float A[SDIM], h[SDIM];
  bool pw = true;
  #pragma unroll
  for (int s = 0; s < SDIM; ++s) {
    A[s] = -__expf(Alog[e * SDIM + s]);
    pw = pw && (fabsf(A[s] + (float)(s + 1)) < 1e-3f * (float)(s + 1));
    h[s] = 0.f;
  }
  float dsum = 0.f;
  if (pw) scan_sum_core<CL, true>(dt, u, Bs, A, h, dsum, n, L, p0, len, dir, e);
  else    scan_sum_core<CL, false>(dt, u, Bs, A, h, dsum, n, L, p0, len, dir, e);
  const size_t set = (size_t)(n * nchunks + c);
  Ps[set * EDIM + e] = dsum;
  const size_t base = (set * EDIM + e) * SDIM;
  #pragma unroll
  for (int s = 0; s < SDIM; ++s) H[base + s] = h[s];
}

// combine: P reconstructed on the fly as exp(A[s]*dsum) — 16x less state traffic
__global__ __launch_bounds__(256)
void em_scan_combine(const float* __restrict__ Psf, const float* __restrict__ Psr,
                     const float* __restrict__ Alogf, const float* __restrict__ Alogr,
                     float* __restrict__ Hfw, float* __restrict__ Hrv, int nchunks) {
  const int dir = blockIdx.z;
  const int idx = blockIdx.x * 256 + threadIdx.x;
  const int n = idx / (EDIM * SDIM);
  const int r = idx % (EDIM * SDIM);
  const int e = r >> 4, s = r & 15;
  const float* Ps = dir ? Psr : Psf;
  const float* Alog = dir ? Alogr : Alogf;
  float* H = dir ? Hrv : Hfw;
  const float As = -__expf(Alog[e * SDIM + s]);
  const size_t st = (size_t)EDIM * SDIM;
  size_t b = (size_t)n * nchunks * st + r;
  size_t db = (size_t)n * nchunks * EDIM + e;
  float h = 0.f;
  for (int c0 = 0; c0 < nchunks; c0 += 8) {
    float pv[8], hf[8];
    #pragma unroll
    for (int q = 0; q < 8; ++q)
      if (c0 + q < nchunks) {
        pv[q] = __expf(As * Ps[db + (size_t)q * EDIM]);
        hf[q] = H[b + (size_t)q * st];
      }
    #pragma unroll
    for (int q = 0; q < 8; ++q)
      if (c0 + q < nchunks) { H[b + (size_t)q * st] = h; h = pv[q] * h + hf[q]; }
    b += 8 * st;
    db += 8 * EDIM;
  }
}

template<int CL, bool PW>
__device__ __forceinline__ void scan_out_core(
    const float* __restrict__ dt, const unsigned short* __restrict__ u,
    const float* __restrict__ xz, unsigned short* __restrict__ y,
    const float (* __restrict__ Bs)[SDIM], const float (* __restrict__ Cs)[SDIM],
    const float* __restrict__ A, float* __restrict__ h, float De,
    int n, int L, int p0, int len, int dir, int e) {
  auto step = [&](int j) {
    const int pos = p0 + j;
    const int l = dir ? (L - 1 - pos) : pos;
    const size_t tok = (size_t)n * L + l;
    const float dtv = dt[tok * EDIM + e];
    const float uv = bf2f(u[tok * EDIM + e]);
    const float dtu = dtv * uv;
    float a[SDIM];
    if (PW) {
      pow_chain16(__expf(-dtv), a);
    } else {
      #pragma unroll
      for (int s = 0; s < SDIM; ++s) a[s] = __expf(dtv * A[s]);
    }
    const float4* b4 = reinterpret_cast<const float4*>(Bs[j]);
    const float4* c4 = reinterpret_cast<const float4*>(Cs[j]);
    float bb[SDIM], cc[SDIM];
    #pragma unroll
    for (int q = 0; q < 4; ++q) {
      const float4 vb = b4[q], vc = c4[q];
      bb[4*q] = vb.x; bb[4*q+1] = vb.y; bb[4*q+2] = vb.z; bb[4*q+3] = vb.w;
      cc[4*q] = vc.x; cc[4*q+1] = vc.y; cc[4*q+2] = vc.z; cc[4*q+3] = vc.w;
    }
    float acc = 0.f;
    #pragma unroll
    for (int s = 0; s < SDIM; ++s) {
      h[s] = a[s] * h[s] + dtu * bb[s];
      acc += h[s] * cc[s];
    }
    const float z = xz[tok * TWOE + EDIM + e];
    y[tok * EDIM + e] = f2bf((acc + uv * De) * em_silu(z));
  };
  if (len == CL) {
    #pragma unroll
    for (int j = 0; j < CL; ++j) step(j);
  } else {
    for (int j = 0; j < len; ++j) step(j);
  }
}

template<int CL>
__global__ __launch_bounds__(256)
void em_scan_out(const float* __restrict__ dtf, const float* __restrict__ dtr,
                 const unsigned short* __restrict__ ubf, const unsigned short* __restrict__ ubr,
                 const float* __restrict__ dblTf, const float* __restrict__ dblTr,
                 const float* __restrict__ xz,
                 const float* __restrict__ Alogf, const float* __restrict__ Alogr,
                 const float* __restrict__ Dpf, const float* __restrict__ Dpr,
                 const float* __restrict__ Hfw, const float* __restrict__ Hrv,
                 unsigned short* __restrict__ ybf, unsigned short* __restrict__ ybr,
                 int L, int nchunks) {
  const int dir = blockIdx.z;
  const int n = blockIdx.y / nchunks;
  const int c = blockIdx.y % nchunks;
  const int tid = threadIdx.x;
  const int e = blockIdx.x * 256 + tid;
  const float* dt = dir ? dtr : dtf;
  const unsigned short* u = dir ? ubr : ubf;
  const float* dblT = dir ? dblTr : dblTf;
  const float* Alog = dir ? Alogr : Alogf;
  const float* Dp = dir ? Dpr : Dpf;
  const float* Hin = dir ? Hrv : Hfw;
  unsigned short* y = dir ? ybr : ybf;
  const int p0 = c * CL;
  const int len = min(CL, L - p0);
  __shared__ __align__(16) float Bs[CL][SDIM];
  __shared__ __align__(16) float Cs[CL][SDIM];
  for (int i = tid; i < CL * 2 * SDIM; i += 256) {
    const int j = i % CL, v = i / CL;
    if (j < len) {
      const int pos = p0 + j;
      const int l = dir ? (L - 1 - pos) : pos;
      const size_t col = (size_t)n * L + l;
      const float val = dblT[(size_t)(RDIM + v) * NTOKS + col]
                      + dblT[(size_t)(64 + RDIM + v) * NTOKS + col];
      if (v < SDIM) Bs[j][v] = val; else Cs[j][v - SDIM] = val;
    }
  }
  __syncthreads();
  float A[SDIM], h[SDIM];
  bool pw = true;
  const size_t base = ((size_t)(n * nchunks + c) * EDIM + e) * SDIM;
  #pragma unroll
  for (int s = 0; s < SDIM; ++s) {
    A[s] = -__expf(Alog[e * SDIM + s]);
    pw = pw && (fabsf(A[s] + (float)(s + 1)) < 1e-3f * (float)(s + 1));
    h[s] = Hin[base + s];
  }
  const float De = Dp[e];
  if (pw) scan_out_core<CL, true>(dt, u, xz, y, Bs, Cs, A, h, De, n, L, p0, len, dir, e);
  else    scan_out_core<CL, false>(dt, u, xz, y, Bs, Cs, A, h, De, n, L, p0, len, dir, e);
}

extern "C" void kernel_launch(void* const* d_in, const int* in_sizes, int n_in,
                              void* d_out, int out_size, void* d_ws, size_t ws_size,
                              hipStream_t stream) {
  const float* x         = (const float*)d_in[0];
  const float* patch_w   = (const float*)d_in[1];
  const float* patch_b   = (const float*)d_in[2];
  const float* cls_tok   = (const float*)d_in[3];
  const float* pos_emb   = (const float*)d_in[4];
  const float* normf     = (const float*)d_in[5];
  const float* sp_conv_w   = (const float*)d_in[6];
  const float* sp_conv_b   = (const float*)d_in[7];
  const float* sp_xproj    = (const float*)d_in[8];
  const float* sp_dtw      = (const float*)d_in[9];
  const float* sp_dtb      = (const float*)d_in[10];
  const float* sp_Alog     = (const float*)d_in[11];
  const float* sp_D        = (const float*)d_in[12];
  const float* sp_conv_w_r = (const float*)d_in[13];
  const float* sp_conv_b_r = (const float*)d_in[14];
  const float* sp_xproj_r  = (const float*)d_in[15];
  const float* sp_dtw_r    = (const float*)d_in[16];
  const float* sp_dtb_r    = (const float*)d_in[17];
  const float* sp_Alog_r   = (const float*)d_in[18];
  const float* sp_D_r      = (const float*)d_in[19];
  const float* tm_conv_w   = (const float*)d_in[20];
  const float* tm_conv_b   = (const float*)d_in[21];
  const float* tm_xproj    = (const float*)d_in[22];
  const float* tm_dtw      = (const float*)d_in[23];
  const float* tm_dtb      = (const float*)d_in[24];
  const float* tm_Alog     = (const float*)d_in[25];
  const float* tm_D        = (const float*)d_in[26];
  const float* sp_norm     = (const float*)d_in[27];
  const float* sp_inproj   = (const float*)d_in[28];
  const float* sp_outproj  = (const float*)d_in[29];
  const float* tm_norm     = (const float*)d_in[30];
  const float* tm_inproj   = (const float*)d_in[31];
  const float* tm_outproj  = (const float*)d_in[32];

  float* ws = (float*)d_ws;
  size_t o = 0;
  float* hidden   = ws + o; o += (size_t)2 * NTOKS * DMODEL;   // 2 K-split slices
  float* hidden2  = hidden + (size_t)NTOKS * DMODEL;
  float* residual = ws + o; o += (size_t)NTOKS * DMODEL;
  float* xz       = ws + o; o += (size_t)NTOKS * TWOE;
  float* dblT_f   = ws + o; o += (size_t)128 * NTOKS;    // 2 K-slices x 64 rows
  float* dblT_r   = ws + o; o += (size_t)128 * NTOKS;
  float* dt_f     = ws + o; o += (size_t)NTOKS * EDIM;
  float* dt_r     = ws + o; o += (size_t)NTOKS * EDIM;
  unsigned short* xn_bf = (unsigned short*)(ws + o); o += (size_t)NTOKS * DMODEL / 2;
  unsigned short* ub_f  = (unsigned short*)(ws + o); o += (size_t)NTOKS * EDIM;      // 2 dirs
  unsigned short* ub_r  = ub_f + (size_t)NTOKS * EDIM;
  unsigned short* yb_f  = (unsigned short*)(ws + o); o += (size_t)NTOKS * EDIM;      // 2 dirs
  unsigned short* yb_r  = yb_f + (size_t)NTOKS * EDIM;

  // ---- bf16 weight caches (converted once per launch) ----
  const size_t n_inproj  = (size_t)NLAYER * TWOE * DMODEL;   // 7.08M each
  const size_t n_outproj = (size_t)NLAYER * DMODEL * EDIM;   // 3.54M each
  const size_t n_xproj   = (size_t)NLAYER * XDIM * EDIM;     // 516K each
  const size_t n_patch   = (size_t)DMODEL * 768;             // 294K
  unsigned short* spin_bf  = (unsigned short*)(ws + o); o += n_inproj / 2;
  unsigned short* tmin_bf  = (unsigned short*)(ws + o); o += n_inproj / 2;
  unsigned short* spout_bf = (unsigned short*)(ws + o); o += n_outproj / 2;
  unsigned short* tmout_bf = (unsigned short*)(ws + o); o += n_outproj / 2;
  unsigned short* spxp_bf  = (unsigned short*)(ws + o); o += n_xproj / 2;
  unsigned short* spxpr_bf = (unsigned short*)(ws + o); o += n_xproj / 2;
  unsigned short* tmxp_bf  = (unsigned short*)(ws + o); o += n_xproj / 2;
  unsigned short* patch_bf = (unsigned short*)(ws + o); o += n_patch / 2;

  // ---- choose scan chunk lengths based on remaining workspace ----
  // per config need: 2 x (sets*EDIM*SDIM) for H + 2 x (sets*EDIM) for dsum
  const size_t avail = (ws_size / sizeof(float) > o) ? (ws_size / sizeof(float) - o) : 0;
  int spCL = 16, tmCL = 8;
  size_t sets = 394;                                   // max(2*197, 16*13)
  auto need = [](size_t s) { return 2 * s * (size_t)EDIM * (SDIM + 1); };
  if (need(sets) > avail) { tmCL = 16; sets = 208; }   // max(2*99, 16*13)
  if (need(sets) > avail) { spCL = 32; sets = 198; }   // original config
  float* scanPs_f = ws + o; o += sets * (size_t)EDIM;
  float* scanPs_r = ws + o; o += sets * (size_t)EDIM;
  float* scanH_f  = ws + o; o += sets * (size_t)EDIM * SDIM;
  float* scanH_r  = ws + o; o += sets * (size_t)EDIM * SDIM;

  unsigned short* im2col_bf = ub_f;            // aliases: unused until first conv
  float* patch_tmp = dt_f;                     // unused until first dtproj

  const int L_sp = 197;
  const int L_tm = 1576;
  const int NC_sp = (L_sp + spCL - 1) / spCL;       // 13 (CL=16) or 7 (CL=32)
  const int NC_tm = (L_tm + tmCL - 1) / tmCL;       // 197 (CL=8) or 99 (CL=16)
  const int MT = (NTOKS + TM - 1) / TM;             // 25
  const int NT64 = (NTOKS + 63) / 64;               // 50
  const int NTC = (NTOKS + CONV_CT - 1) / CONV_CT;  // 197 conv token-chunks
  const int NT16 = NTOKS / DT_TT;                   // 197 dtproj token-tiles

  // -------- weight pre-conversion (8 dispatches, ~140 MB total) --------
  auto cvt = [&](const float* s, unsigned short* d, size_t n) {
    em_f2bf_arr<<<(unsigned)((n / 4 + 255) / 256), 256, 0, stream>>>(s, d, n);
  };
  cvt(sp_inproj, spin_bf, n_inproj);
  cvt(tm_inproj, tmin_bf, n_inproj);
  cvt(sp_outproj, spout_bf, n_outproj);
  cvt(tm_outproj, tmout_bf, n_outproj);
  cvt(sp_xproj, spxp_bf, n_xproj);
  cvt(sp_xproj_r, spxpr_bf, n_xproj);
  cvt(tm_xproj, tmxp_bf, n_xproj);
  cvt(patch_w, patch_bf, n_patch);

  // -------- patch embed: im2col(bf16) + MFMA GEMM + fused epilogue/norm --------
  em_im2col<<<(NPATCH * 768) / 256, 256, 0, stream>>>(x, im2col_bf);
  em_gemm_abf<<<dim3(DMODEL / TN, (NPATCH + TM - 1) / TM, 1), 256, 0, stream>>>(
      im2col_bf, nullptr, patch_bf, patch_tmp, NPATCH, DMODEL, 768, 768);
  em_embed_norm<<<NTOKS, DMODEL, 0, stream>>>(patch_tmp, patch_b, cls_tok, pos_emb,
                                              sp_norm, residual, xn_bf);

  // -------- 12 spatial bimamba blocks: N=16 sequences of L=197 --------
  for (int i = 0; i < NLAYER; ++i) {
    const float* Alf = sp_Alog + (size_t)i * EDIM * SDIM;
    const float* Alr = sp_Alog_r + (size_t)i * EDIM * SDIM;
    em_gemm_abf<<<dim3(TWOE / TN, MT, 1), 256, 0, stream>>>(
        xn_bf, nullptr, spin_bf + (size_t)i * TWOE * DMODEL, xz, NTOKS, TWOE, DMODEL, DMODEL);
    em_conv_silu<<<dim3(EDIM / 256, NTC, 2), 256, 0, stream>>>(
        xz, sp_conv_w + (size_t)i * EDIM * 4, sp_conv_b + (size_t)i * EDIM,
        sp_conv_w_r + (size_t)i * EDIM * 4, sp_conv_b_r + (size_t)i * EDIM,
        ub_f, ub_r, L_sp);
    em_gemm_xpT<<<dim3(NT64, 2, 2), 256, 0, stream>>>(
        ub_f, ub_r, spxp_bf + (size_t)i * XDIM * EDIM, spxpr_bf + (size_t)i * XDIM * EDIM,
        dblT_f, dblT_r);
    em_dtproj<<<dim3(EDIM / 256, NT16, 2), 256, 0, stream>>>(
        dblT_f, dblT_r, sp_dtw + (size_t)i * EDIM * RDIM, sp_dtw_r + (size_t)i * EDIM * RDIM,
        sp_dtb + (size_t)i * EDIM, sp_dtb_r + (size_t)i * EDIM, dt_f, dt_r);
    if (spCL == 16)
      em_scan_sum<16><<<dim3(EDIM / 256, 16 * NC_sp, 2), 256, 0, stream>>>(
          dt_f, dt_r, ub_f, ub_r, dblT_f, dblT_r, Alf, Alr,
          scanPs_f, scanPs_r, scanH_f, scanH_r, L_sp, NC_sp);
    else
      em_scan_sum<32><<<dim3(EDIM / 256, 16 * NC_sp, 2), 256, 0, stream>>>(
          dt_f, dt_r, ub_f, ub_r, dblT_f, dblT_r, Alf, Alr,
          scanPs_f, scanPs_r, scanH_f, scanH_r, L_sp, NC_sp);
    em_scan_combine<<<dim3(16 * EDIM * SDIM / 256, 1, 2), 256, 0, stream>>>(
        scanPs_f, scanPs_r, Alf, Alr, scanH_f, scanH_r, NC_sp);
    if (spCL == 16)
      em_scan_out<16><<<dim3(EDIM / 256, 16 * NC_sp, 2), 256, 0, stream>>>(
          dt_f, dt_r, ub_f, ub_r, dblT_f, dblT_r, xz, Alf, Alr,
          sp_D + (size_t)i * EDIM, sp_D_r + (size_t)i * EDIM,
          scanH_f, scanH_r, yb_f, yb_r, L_sp, NC_sp);
    else
      em_scan_out<32><<<dim3(EDIM / 256, 16 * NC_sp, 2), 256, 0, stream>>>(
          dt_f, dt_r, ub_f, ub_r, dblT_f, dblT_r, xz, Alf, Alr,
          sp_D + (size_t)i * EDIM, sp_D_r + (size_t)i * EDIM,
          scanH_f, scanH_r, yb_f, yb_r, L_sp, NC_sp);
    em_gemm_abf<<<dim3(DMODEL / TN, MT, 2), 256, 0, stream>>>(
        yb_f, yb_r, spout_bf + (size_t)i * DMODEL * EDIM, hidden, NTOKS, DMODEL, EDIM / 2, EDIM);
    const float* next_w = (i < NLAYER - 1) ? sp_norm + (size_t)(i + 1) * DMODEL : tm_norm;
    em_add_rmsnorm<<<NTOKS, DMODEL, 0, stream>>>(hidden, hidden2, residual, residual,
                                                 next_w, nullptr, xn_bf);
  }

  // -------- 12 temporal mamba blocks: N=2 sequences of L=1576 --------
  for (int i = 0; i < NLAYER; ++i) {
    const float* Al = tm_Alog + (size_t)i * EDIM * SDIM;
    em_gemm_abf<<<dim3(TWOE / TN, MT, 1), 256, 0, stream>>>(
        xn_bf, nullptr, tmin_bf + (size_t)i * TWOE * DMODEL, xz, NTOKS, TWOE, DMODEL, DMODEL);
    em_conv_silu<<<dim3(EDIM / 256, NTC, 1), 256, 0, stream>>>(
        xz, tm_conv_w + (size_t)i * EDIM * 4, tm_conv_b + (size_t)i * EDIM,
        tm_conv_w + (size_t)i * EDIM * 4, tm_conv_b + (size_t)i * EDIM,
        ub_f, ub_r, L_tm);
    em_gemm_xpT<<<dim3(NT64, 2, 1), 256, 0, stream>>>(
        ub_f, ub_r, tmxp_bf + (size_t)i * XDIM * EDIM, tmxp_bf + (size_t)i * XDIM * EDIM,
        dblT_f, dblT_r);
    em_dtproj<<<dim3(EDIM / 256, NT16, 1), 256, 0, stream>>>(
        dblT_f, dblT_r, tm_dtw + (size_t)i * EDIM * RDIM, tm_dtw + (size_t)i * EDIM * RDIM,
        tm_dtb + (size_t)i * EDIM, tm_dtb + (size_t)i * EDIM, dt_f, dt_r);
    if (tmCL == 8)
      em_scan_sum<8><<<dim3(EDIM / 256, 2 * NC_tm, 1), 256, 0, stream>>>(
          dt_f, dt_r, ub_f, ub_r, dblT_f, dblT_r, Al, Al,
          scanPs_f, scanPs_r, scanH_f, scanH_r, L_tm, NC_tm);
    else
      em_scan_sum<16><<<dim3(EDIM / 256, 2 * NC_tm, 1), 256, 0, stream>>>(
          dt_f, dt_r, ub_f, ub_r, dblT_f, dblT_r, Al, Al,
          scanPs_f, scanPs_r, scanH_f, scanH_r, L_tm, NC_tm);
    em_scan_combine<<<dim3(2 * EDIM * SDIM / 256, 1, 1), 256, 0, stream>>>(
        scanPs_f, scanPs_r, Al, Al, scanH_f, scanH_r, NC_tm);
    if (tmCL == 8)
      em_scan_out<8><<<dim3(EDIM / 256, 2 * NC_tm, 1), 256, 0, stream>>>(
          dt_f, dt_r, ub_f, ub_r, dblT_f, dblT_r, xz, Al, Al,
          tm_D + (size_t)i * EDIM, tm_D + (size_t)i * EDIM,
          scanH_f, scanH_r, yb_f, yb_r, L_tm, NC_tm);
    else
      em_scan_out<16><<<dim3(EDIM / 256, 2 * NC_tm, 1), 256, 0, stream>>>(
          dt_f, dt_r, ub_f, ub_r, dblT_f, dblT_r, xz, Al, Al,
          tm_D + (size_t)i * EDIM, tm_D + (size_t)i * EDIM,
          scanH_f, scanH_r, yb_f, yb_r, L_tm, NC_tm);
    em_gemm_abf<<<dim3(DMODEL / TN, MT, 2), 256, 0, stream>>>(
        yb_f, nullptr, tmout_bf + (size_t)i * DMODEL * EDIM, hidden, NTOKS, DMODEL, EDIM / 2, EDIM);
    const bool last = (i == NLAYER - 1);
    const float* next_w = last ? normf : tm_norm + (size_t)(i + 1) * DMODEL;
    em_add_rmsnorm<<<NTOKS, DMODEL, 0, stream>>>(hidden, hidden2, residual,
                                                 last ? nullptr : residual,
                                                 next_w, last ? (float*)d_out : nullptr,
                                                 last ? nullptr : xn_bf);
  }
}

// Round 8
// 3595.901 us; speedup vs baseline: 1.0038x; 1.0038x over previous
//
#include <hip/hip_runtime.h>

#define NTOKS 3152      // B*T*P = 2*8*197
#define DMODEL 384
#define EDIM 768
#define TWOE 1536
#define SDIM 16
#define RDIM 24
#define XDIM 56         // R + 2S
#define NLAYER 12
#define NPATCH 3136     // 16 * 196

typedef __attribute__((ext_vector_type(8))) short bf16x8;
typedef __attribute__((ext_vector_type(4))) float f32x4;

__device__ __forceinline__ float em_silu(float v) { return v / (1.f + __expf(-v)); }

__device__ __forceinline__ unsigned short f2bf(float f) {
  union { float f; unsigned int u; } v; v.f = f;
  const unsigned int r = v.u + 0x7fffu + ((v.u >> 16) & 1u);   // RTNE
  return (unsigned short)(r >> 16);
}
__device__ __forceinline__ unsigned int f2bf2(float lo, float hi) {
  return (unsigned int)f2bf(lo) | ((unsigned int)f2bf(hi) << 16);
}
__device__ __forceinline__ float bf2f(unsigned short s) {
  union { unsigned int u; float f; } v; v.u = (unsigned int)s << 16; return v.f;
}
__device__ __forceinline__ float bfbits_lo(unsigned int u) {
  union { unsigned int u; float f; } v; v.u = u << 16; return v.f;
}
__device__ __forceinline__ float bfbits_hi(unsigned int u) {
  union { unsigned int u; float f; } v; v.u = u & 0xffff0000u; return v.f;
}
__device__ __forceinline__ unsigned int addbf2(unsigned int a, unsigned int b) {
  return f2bf2(bfbits_lo(a) + bfbits_lo(b), bfbits_hi(a) + bfbits_hi(b));
}
__device__ __forceinline__ uint4 addbf8(uint4 a, uint4 b) {
  uint4 r;
  r.x = addbf2(a.x, b.x); r.y = addbf2(a.y, b.y);
  r.z = addbf2(a.z, b.z); r.w = addbf2(a.w, b.w);
  return r;
}
// fast softplus: max(a,0) + log(1+exp(-|a|)); native v_exp/v_log, abs err ~1e-6
__device__ __forceinline__ float em_softplus(float a) {
  const float t = __expf(-fabsf(a));
  return fmaxf(a, 0.f) + __logf(1.f + t);
}

// a[s] = q^(s+1) for s=0..15, log-depth product chain (depth 4, 18 muls)
__device__ __forceinline__ void pow_chain16(float q, float* a) {
  const float q2 = q * q, q4 = q2 * q2, q8 = q4 * q4;
  a[0] = q;       a[1] = q2;      a[2] = q2 * q;  a[3] = q4;
  a[4] = q4 * q;  a[5] = q4 * q2; a[6] = q4 * a[2]; a[7] = q8;
  a[8] = q8 * q;  a[9] = q8 * q2; a[10] = q8 * a[2]; a[11] = q8 * q4;
  a[12] = q8 * a[4]; a[13] = q8 * a[5]; a[14] = q8 * a[6]; a[15] = q8 * q8;
}

// ---------------- fp32 -> bf16 weight pre-conversion (n % 4 == 0) ----------------
__global__ __launch_bounds__(256)
void em_f2bf_arr(const float* __restrict__ s, unsigned short* __restrict__ d, size_t n) {
  const size_t i = ((size_t)blockIdx.x * 256 + threadIdx.x) * 4;
  if (i < n) {
    const float4 v = *reinterpret_cast<const float4*>(s + i);
    uint2 pk;
    pk.x = f2bf2(v.x, v.y); pk.y = f2bf2(v.z, v.w);
    *reinterpret_cast<uint2*>(d + i) = pk;
  }
}

// ---------------- im2col (bf16 out) for patch embed: col[3136][768] ----------------
__global__ __launch_bounds__(256)
void em_im2col(const float* __restrict__ x, unsigned short* __restrict__ col) {
  const int g = blockIdx.x * 256 + threadIdx.x;   // pr*768 + cc
  const int pr = g / 768;
  const int cc = g - pr * 768;
  const int np = pr % 196;
  const int bt = pr / 196;
  const int t = bt & 7, b = bt >> 3;
  const int hp = np / 14, wp = np - hp * 14;
  const int c = cc >> 8;
  const int rem = cc & 255;
  const int ph = rem >> 4, pw = rem & 15;
  col[g] = f2bf(x[(((size_t)(b * 3 + c) * 8 + t) * 224 + (hp * 16 + ph)) * 224 + (wp * 16 + pw)]);
}

// -------- patch embed epilogue fused with first residual+RMSNorm --------
__global__ __launch_bounds__(DMODEL)
void em_embed_norm(const float* __restrict__ tmpP, const float* __restrict__ pb,
                   const float* __restrict__ cls, const float* __restrict__ pos,
                   const float* __restrict__ w,
                   float* __restrict__ residual, unsigned short* __restrict__ xn_bf) {
  const int tok = blockIdx.x;
  const int d = threadIdx.x;
  const int p = tok % 197;
  const int bt = tok / 197;
  const int t = bt & 7;
  float v;
  if (p == 0) {
    v = cls[d] + pos[d];
  } else {
    const int np = p - 1;
    const float div = powf(10000.f, (float)(d & ~1) * (1.f / 384.f));
    const float ang = (float)t / div;
    const float enc = (d & 1) ? cosf(ang) : sinf(ang);
    v = tmpP[((size_t)bt * 196 + np) * DMODEL + d] + pb[d] + pos[(size_t)p * DMODEL + d] + enc;
  }
  const size_t idx = (size_t)tok * DMODEL + d;
  residual[idx] = v;
  float ss = v * v;
  #pragma unroll
  for (int off = 32; off; off >>= 1) ss += __shfl_xor(ss, off, 64);
  __shared__ float red[6];
  if ((d & 63) == 0) red[d >> 6] = ss;
  __syncthreads();
  float tot = 0.f;
  #pragma unroll
  for (int i = 0; i < 6; ++i) tot += red[i];
  const float scale = rsqrtf(tot * (1.f / 384.f) + 1e-5f);
  xn_bf[idx] = f2bf(v * scale * w[d]);
}

// ------- residual add (+ optional K-split partial) + RMSNorm; bf16 (layers) / fp32 (final) -----
__global__ __launch_bounds__(DMODEL)
void em_add_rmsnorm(const float* __restrict__ hidden, const float* __restrict__ hidden2,
                    const float* __restrict__ res_in,
                    float* __restrict__ res_out, const float* __restrict__ w,
                    float* __restrict__ out, unsigned short* __restrict__ out_bf) {
  const int tok = blockIdx.x;
  const int d = threadIdx.x;
  const size_t idx = (size_t)tok * DMODEL + d;
  float v = hidden[idx] + res_in[idx];
  if (hidden2) v += hidden2[idx];
  if (res_out) res_out[idx] = v;
  float ss = v * v;
  #pragma unroll
  for (int off = 32; off; off >>= 1) ss += __shfl_xor(ss, off, 64);
  __shared__ float red[6];
  if ((d & 63) == 0) red[d >> 6] = ss;
  __syncthreads();
  float tot = 0.f;
  #pragma unroll
  for (int i = 0; i < 6; ++i) tot += red[i];
  const float scale = rsqrtf(tot * (1.f / 384.f) + 1e-5f);
  const float r = v * scale * w[d];
  if (out_bf) out_bf[idx] = f2bf(r);
  else out[idx] = r;
}

// ====== MFMA GEMM, bf16 A (+A2) and bf16 W, LDS ping-pong double-buffer, optional K-split ======
// grid: (N/TN, ceil(M/TM), nks); K = per-slice length, KS = full row stride.
#define TM 128
#define TN 64
#define LDT 40   // ushorts per LDS row (32 + 8 pad)
__global__ __launch_bounds__(256)
void em_gemm_abf(const unsigned short* __restrict__ A, const unsigned short* __restrict__ A2,
                 const unsigned short* __restrict__ W, float* __restrict__ C,
                 int M, int N, int K, int KS) {
  __shared__ unsigned short As[2][TM * LDT];
  __shared__ unsigned short Bs[2][TN * LDT];
  const int tid = threadIdx.x;
  const int bm = blockIdx.y * TM;
  const int bn = blockIdx.x * TN;
  const int kk0 = blockIdx.z * K;
  const int kkend = kk0 + K;
  const int wave = tid >> 6, lane = tid & 63;
  const int wm = (wave >> 1) * 64, wn = (wave & 1) * 32;
  const int mq = lane & 15, quad = lane >> 4;
  f32x4 acc[4][2] = {};
  const int ar = tid >> 1;
  const int ah = (tid & 1) * 16;
  const int br = tid >> 2;
  const int bk = (tid & 3) * 8;
  const int arow = bm + ar;

  uint4 a0, a1, b0;
  auto load_tile = [&](int kk) {
    a0 = {0, 0, 0, 0}; a1 = {0, 0, 0, 0};
    if (arow < M) {
      const uint4* pa = reinterpret_cast<const uint4*>(A + (size_t)arow * KS + kk + ah);
      a0 = pa[0]; a1 = pa[1];
      if (A2) {
        const uint4* pb = reinterpret_cast<const uint4*>(A2 + (size_t)arow * KS + kk + ah);
        a0 = addbf8(a0, pb[0]); a1 = addbf8(a1, pb[1]);
      }
    }
    b0 = *reinterpret_cast<const uint4*>(W + (size_t)(bn + br) * KS + kk + bk);
  };
  auto store_tile = [&](int buf) {
    uint4* dst = reinterpret_cast<uint4*>(&As[buf][ar * LDT + ah]);
    dst[0] = a0; dst[1] = a1;
    *reinterpret_cast<uint4*>(&Bs[buf][br * LDT + bk]) = b0;
  };

  load_tile(kk0);
  store_tile(0);
  __syncthreads();
  int cur = 0;
  for (int kk = kk0; kk < kkend; kk += 32) {
    const bool have = (kk + 32) < kkend;
    if (have) load_tile(kk + 32);
    bf16x8 bfr[2];
    #pragma unroll
    for (int j = 0; j < 2; ++j)
      bfr[j] = *reinterpret_cast<const bf16x8*>(&Bs[cur][(wn + j * 16 + mq) * LDT + quad * 8]);
    #pragma unroll
    for (int i = 0; i < 4; ++i) {
      const bf16x8 afr = *reinterpret_cast<const bf16x8*>(&As[cur][(wm + i * 16 + mq) * LDT + quad * 8]);
      acc[i][0] = __builtin_amdgcn_mfma_f32_16x16x32_bf16(afr, bfr[0], acc[i][0], 0, 0, 0);
      acc[i][1] = __builtin_amdgcn_mfma_f32_16x16x32_bf16(afr, bfr[1], acc[i][1], 0, 0, 0);
    }
    if (have) {
      store_tile(cur ^ 1);
      __syncthreads();
      cur ^= 1;
    }
  }
  float* Cz = C + (size_t)blockIdx.z * M * N;
  #pragma unroll
  for (int i = 0; i < 4; ++i) {
    const int mbase = bm + wm + i * 16 + quad * 4;
    #pragma unroll
    for (int j = 0; j < 2; ++j) {
      const int col = bn + wn + j * 16 + mq;
      #pragma unroll
      for (int p = 0; p < 4; ++p) {
        const int m = mbase + p;
        if (m < M) Cz[(size_t)m * N + col] = acc[i][j][p];
      }
    }
  }
}

// ===== transposed xproj GEMM (bf16 W), K-split x2, LDS ping-pong double-buffer:
//       dblT[slice][64][NTOKS] = xp[56, Kslice] @ u[:, Kslice]^T ; consumers sum slices =====
// grid: (ceil(NTOKS/64), 2, dirs)
__global__ __launch_bounds__(256)
void em_gemm_xpT(const unsigned short* __restrict__ ubf, const unsigned short* __restrict__ ubr,
                 const unsigned short* __restrict__ xpf, const unsigned short* __restrict__ xpr,
                 float* __restrict__ dblTf, float* __restrict__ dblTr) {
  const int dir = blockIdx.z;
  const int ks = blockIdx.y;                // K slice: 0..1
  const unsigned short* U = dir ? ubr : ubf;
  const unsigned short* W = dir ? xpr : xpf;
  float* C = dir ? dblTr : dblTf;
  __shared__ unsigned short As[2][64 * LDT];   // xp tile (56 real rows)
  __shared__ unsigned short Bs[2][64 * LDT];   // u tile (64 tokens)
  const int tid = threadIdx.x;
  const int bn = blockIdx.x * 64;           // token base
  const int wave = tid >> 6, lane = tid & 63;
  const int wm = wave * 16;
  const int mq = lane & 15, quad = lane >> 4;
  f32x4 acc[4] = {};
  const int sr = tid >> 2;
  const int sq = (tid & 3) * 8;
  const int k0 = ks * (EDIM / 2), k1 = k0 + EDIM / 2;
  const int btok = bn + sr;

  uint4 wa, ub;
  auto load_tile = [&](int kk) {
    wa = {0, 0, 0, 0}; ub = {0, 0, 0, 0};
    if (sr < XDIM)
      wa = *reinterpret_cast<const uint4*>(W + (size_t)sr * EDIM + kk + sq);
    if (btok < NTOKS)
      ub = *reinterpret_cast<const uint4*>(U + (size_t)btok * EDIM + kk + sq);
  };
  auto store_tile = [&](int buf) {
    *reinterpret_cast<uint4*>(&As[buf][sr * LDT + sq]) = wa;
    *reinterpret_cast<uint4*>(&Bs[buf][sr * LDT + sq]) = ub;
  };

  load_tile(k0);
  store_tile(0);
  __syncthreads();
  int cur = 0;
  for (int kk = k0; kk < k1; kk += 32) {
    const bool have = (kk + 32) < k1;
    if (have) load_tile(kk + 32);
    const bf16x8 afr = *reinterpret_cast<const bf16x8*>(&As[cur][(wm + mq) * LDT + quad * 8]);
    #pragma unroll
    for (int j = 0; j < 4; ++j) {
      const bf16x8 bfr = *reinterpret_cast<const bf16x8*>(&Bs[cur][(j * 16 + mq) * LDT + quad * 8]);
      acc[j] = __builtin_amdgcn_mfma_f32_16x16x32_bf16(afr, bfr, acc[j], 0, 0, 0);
    }
    if (have) {
      store_tile(cur ^ 1);
      __syncthreads();
      cur ^= 1;
    }
  }
  #pragma unroll
  for (int j = 0; j < 4; ++j) {
    const int tok = bn + j * 16 + mq;
    if (tok < NTOKS) {
      #pragma unroll
      for (int p = 0; p < 4; ++p) {
        const int m = wm + quad * 4 + p;
        C[(size_t)(ks * 64 + m) * NTOKS + tok] = acc[j][p];
      }
    }
  }
}

// ---------------- dt projection: dt[tok][e] = softplus(r(tok)·dtw[e] + dtb[e]) ----------------
// grid: (EDIM/256, NTOKS/16, dirs)
#define DT_TT 16
__global__ __launch_bounds__(256)
void em_dtproj(const float* __restrict__ dblTf, const float* __restrict__ dblTr,
               const float* __restrict__ dtwf, const float* __restrict__ dtwr,
               const float* __restrict__ dtbf, const float* __restrict__ dtbr,
               float* __restrict__ dtf, float* __restrict__ dtr) {
  const int e = blockIdx.x * 256 + threadIdx.x;
  const int t0 = blockIdx.y * DT_TT;
  const int dir = blockIdx.z;
  const float* dblT = dir ? dblTr : dblTf;
  const float* dtw = dir ? dtwr : dtwf;
  const float* dtb = dir ? dtbr : dtbf;
  float* dto = dir ? dtr : dtf;
  __shared__ float r[DT_TT][RDIM + 1];   // +1 pad: odd stride, conflict-free
  for (int i = threadIdx.x; i < DT_TT * RDIM; i += 256) {   // 384 entries, 256 threads
    const int tt = i & (DT_TT - 1);
    const int j = i >> 4;
    const int tok = t0 + tt;                                // NTOKS % 16 == 0: always valid
    r[tt][j] = dblT[(size_t)j * NTOKS + tok] + dblT[(size_t)(64 + j) * NTOKS + tok];
  }
  __syncthreads();
  const float4* wp = reinterpret_cast<const float4*>(dtw + (size_t)e * RDIM);  // 96B aligned
  float w[RDIM];
  #pragma unroll
  for (int q = 0; q < 6; ++q) {
    const float4 v = wp[q];
    w[q * 4 + 0] = v.x; w[q * 4 + 1] = v.y; w[q * 4 + 2] = v.z; w[q * 4 + 3] = v.w;
  }
  const float b = dtb[e];
  float* o = dto + (size_t)t0 * EDIM + e;
  #pragma unroll 4
  for (int tt = 0; tt < DT_TT; ++tt) {
    float a = b;
    #pragma unroll
    for (int j = 0; j < RDIM; ++j) a += r[tt][j] * w[j];   // LDS broadcast reads
    o[(size_t)tt * EDIM] = em_softplus(a);
  }
}

// ---------------- depthwise conv + SiLU; sliding register window, 16 tokens/thread ------------
// grid: (EDIM/256, ceil(NTOKS/16), dirs)
#define CONV_CT 16
__global__ __launch_bounds__(256)
void em_conv_silu(const float* __restrict__ xz,
                  const float* __restrict__ cwf, const float* __restrict__ cbf,
                  const float* __restrict__ cwr, const float* __restrict__ cbr,
                  unsigned short* __restrict__ ubf, unsigned short* __restrict__ ubr, int L) {
  const int e = blockIdx.x * 256 + threadIdx.x;
  const int t0 = blockIdx.y * CONV_CT;
  const int dir = blockIdx.z;
  const float* cw = dir ? cwr : cwf;
  const float* cb = dir ? cbr : cbf;
  unsigned short* out = dir ? ubr : ubf;
  const float4 wv = *reinterpret_cast<const float4*>(cw + e * 4);
  const float w0 = wv.x, w1 = wv.y, w2 = wv.z, w3 = wv.w;
  const float bv = cb[e];
  const float* xcol = xz + e;               // u-half column of xz, stride TWOE per token
  int l = t0 % L;
  if (dir == 0) {
    float xm1 = (l >= 1) ? xcol[(size_t)(t0 - 1) * TWOE] : 0.f;
    float xm2 = (l >= 2) ? xcol[(size_t)(t0 - 2) * TWOE] : 0.f;
    float xm3 = (l >= 3) ? xcol[(size_t)(t0 - 3) * TWOE] : 0.f;
    for (int tt = 0; tt < CONV_CT; ++tt) {
      const int tok = t0 + tt;
      if (tok >= NTOKS) break;
      const float xc = xcol[(size_t)tok * TWOE];
      float acc = bv + xc * w3;
      if (l >= 1) acc += xm1 * w2;
      if (l >= 2) acc += xm2 * w1;
      if (l >= 3) acc += xm3 * w0;
      out[(size_t)tok * EDIM + e] = f2bf(em_silu(acc));
      xm3 = xm2; xm2 = xm1; xm1 = xc;
      if (++l == L) l = 0;                  // new sequence: guards zero stale window
    }
  } else {
    float xc  = xcol[(size_t)t0 * TWOE];
    float xp1 = (t0 + 1 < NTOKS) ? xcol[(size_t)(t0 + 1) * TWOE] : 0.f;
    float xp2 = (t0 + 2 < NTOKS) ? xcol[(size_t)(t0 + 2) * TWOE] : 0.f;
    for (int tt = 0; tt < CONV_CT; ++tt) {
      const int tok = t0 + tt;
      if (tok >= NTOKS) break;
      const float xp3 = (tok + 3 < NTOKS) ? xcol[(size_t)(tok + 3) * TWOE] : 0.f;
      float acc = bv + xc * w3;
      if (l + 1 < L) acc += xp1 * w2;
      if (l + 2 < L) acc += xp2 * w1;
      if (l + 3 < L) acc += xp3 * w0;
      out[(size_t)tok * EDIM + e] = f2bf(em_silu(acc));
      xc = xp1; xp1 = xp2; xp2 = xp3;
      if (++l == L) l = 0;
    }
  }
}

// ================= chunked scan (templated chunk length) =================
// PW path: A[s] == -(s+1) (verified at runtime) -> exp(dtv*A[s]) = q^(s+1), q=exp(-dtv).
// Chunk decay product stored COMPRESSED as dsum: P[s] = exp(A[s]*dsum) exactly, for any A.
template<int CL, bool PW>
__device__ __forceinline__ void scan_sum_core(
    const float* __restrict__ dt, const unsigned short* __restrict__ u,
    const float (* __restrict__ Bs)[SDIM], const float* __restrict__ A,
    float* __restrict__ h, float& dsum,
    int n, int L, int p0, int len, int dir, int e) {
  auto step = [&](int j) {
    const int pos = p0 + j;
    const int l = dir ? (L - 1 - pos) : pos;
    const size_t tok = (size_t)n * L + l;
    const float dtv = dt[tok * EDIM + e];
    const float dtu = dtv * bf2f(u[tok * EDIM + e]);
    dsum += dtv;
    float a[SDIM];
    if (PW) {
      pow_chain16(__expf(-dtv), a);
    } else {
      #pragma unroll
      for (int s = 0; s < SDIM; ++s) a[s] = __expf(dtv * A[s]);
    }
    const float4* b4 = reinterpret_cast<const float4*>(Bs[j]);
    float bb[SDIM];
    #pragma unroll
    for (int q = 0; q < 4; ++q) {
      const float4 v = b4[q];
      bb[4*q] = v.x; bb[4*q+1] = v.y; bb[4*q+2] = v.z; bb[4*q+3] = v.w;
    }
    #pragma unroll
    for (int s = 0; s < SDIM; ++s) h[s] = a[s] * h[s] + dtu * bb[s];
  };
  if (len == CL) {
    #pragma unroll
    for (int j = 0; j < CL; ++j) step(j);
  } else {
    for (int j = 0; j < len; ++j) step(j);
  }
}

template<int CL>
__global__ __launch_bounds__(256)
void em_scan_sum(const float* __restrict__ dtf, const float* __restrict__ dtr,
                 const unsigned short* __restrict__ ubf, const unsigned short* __restrict__ ubr,
                 const float* __restrict__ dblTf, const float* __restrict__ dblTr,
                 const float* __restrict__ Alogf, const float* __restrict__ Alogr,
                 float* __restrict__ Psf, float* __restrict__ Psr,
                 float* __restrict__ Hfw, float* __restrict__ Hrv,
                 int L, int nchunks) {
  const int dir = blockIdx.z;
  const int n = blockIdx.y / nchunks;
  const int c = blockIdx.y % nchunks;
  const int tid = threadIdx.x;
  const int e = blockIdx.x * 256 + tid;
  const float* dt = dir ? dtr : dtf;
  const unsigned short* u = dir ? ubr : ubf;
  const float* dblT = dir ? dblTr : dblTf;
  const float* Alog = dir ? Alogr : Alogf;
  float* Ps = dir ? Psr : Psf;
  float* H = dir ? Hrv : Hfw;
  const int p0 = c * CL;
  const int len = min(CL, L - p0);
  __shared__ __align__(16) float Bs[CL][SDIM];
  for (int i = tid; i < CL * SDIM; i += 256) {
    const int j = i % CL, s = i / CL;
    if (j < len) {
      const int pos = p0 + j;
      const int l = dir ? (L - 1 - pos) : pos;
      const size_t col = (size_t)n * L + l;
      Bs[j][s] = dblT[(size_t)(RDIM + s) * NTOKS + col]
               + dblT[(size_t)(64 + RDIM + s) * NTOKS + col];
    }
  }
  __syncthreads();
  float A[SDIM], h[SDIM];
  bool pw = true;
  #pragma unroll
  for (int s = 0; s < SDIM; ++s) {
    A[s] = -__expf(Alog[e * SDIM + s]);
    pw = pw && (fabsf(A[s] + (float)(s + 1)) < 1e-3f * (float)(s + 1));
    h[s] = 0.f;
  }
  float dsum = 0.f;
  if (pw) scan_sum_core<CL, true>(dt, u, Bs, A, h, dsum, n, L, p0, len, dir, e);
  else    scan_sum_core<CL, false>(dt, u, Bs, A, h, dsum, n, L, p0, len, dir, e);
  const size_t set = (size_t)(n * nchunks + c);
  Ps[set * EDIM + e] = dsum;
  const size_t base = (set * EDIM + e) * SDIM;
  #pragma unroll
  for (int s = 0; s < SDIM; ++s) H[base + s] = h[s];
}

// combine: P reconstructed on the fly as exp(A[s]*dsum); batch-16 deep for latency hiding
__global__ __launch_bounds__(256)
void em_scan_combine(const float* __restrict__ Psf, const float* __restrict__ Psr,
                     const float* __restrict__ Alogf, const float* __restrict__ Alogr,
                     float* __restrict__ Hfw, float* __restrict__ Hrv, int nchunks) {
  const int dir = blockIdx.z;
  const int idx = blockIdx.x * 256 + threadIdx.x;
  const int n = idx / (EDIM * SDIM);
  const int r = idx % (EDIM * SDIM);
  const int e = r >> 4, s = r & 15;
  const float* Ps = dir ? Psr : Psf;
  const float* Alog = dir ? Alogr : Alogf;
  float* H = dir ? Hrv : Hfw;
  const float As = -__expf(Alog[e * SDIM + s]);
  const size_t st = (size_t)EDIM * SDIM;
  size_t b = (size_t)n * nchunks * st + r;
  size_t db = (size_t)n * nchunks * EDIM + e;
  float h = 0.f;
  for (int c0 = 0; c0 < nchunks; c0 += 16) {
    float pv[16], hf[16];
    #pragma unroll
    for (int q = 0; q < 16; ++q)
      if (c0 + q < nchunks) {
        pv[q] = __expf(As * Ps[db + (size_t)q * EDIM]);
        hf[q] = H[b + (size_t)q * st];
      }
    #pragma unroll
    for (int q = 0; q < 16; ++q)
      if (c0 + q < nchunks) { H[b + (size_t)q * st] = h; h = pv[q] * h + hf[q]; }
    b += 16 * st;
    db += 16 * EDIM;
  }
}

template<int CL, bool PW>
__device__ __forceinline__ void scan_out_core(
    const float* __restrict__ dt, const unsigned short* __restrict__ u,
    const float* __restrict__ xz, unsigned short* __restrict__ y,
    const float (* __restrict__ Bs)[SDIM], const float (* __restrict__ Cs)[SDIM],
    const float* __restrict__ A, float* __restrict__ h, float De,
    int n, int L, int p0, int len, int dir, int e) {
  auto step = [&](int j) {
    const int pos = p0 + j;
    const int l = dir ? (L - 1 - pos) : pos;
    const size_t tok = (size_t)n * L + l;
    const float dtv = dt[tok * EDIM + e];
    const float uv = bf2f(u[tok * EDIM + e]);
    const float dtu = dtv * uv;
    float a[SDIM];
    if (PW) {
      pow_chain16(__expf(-dtv), a);
    } else {
      #pragma unroll
      for (int s = 0; s < SDIM; ++s) a[s] = __expf(dtv * A[s]);
    }
    const float4* b4 = reinterpret_cast<const float4*>(Bs[j]);
    const float4* c4 = reinterpret_cast<const float4*>(Cs[j]);
    float bb[SDIM], cc[SDIM];
    #pragma unroll
    for (int q = 0; q < 4; ++q) {
      const float4 vb = b4[q], vc = c4[q];
      bb[4*q] = vb.x; bb[4*q+1] = vb.y; bb[4*q+2] = vb.z; bb[4*q+3] = vb.w;
      cc[4*q] = vc.x; cc[4*q+1] = vc.y; cc[4*q+2] = vc.z; cc[4*q+3] = vc.w;
    }
    float acc = 0.f;
    #pragma unroll
    for (int s = 0; s < SDIM; ++s) {
      h[s] = a[s] * h[s] + dtu * bb[s];
      acc += h[s] * cc[s];
    }
    const float z = xz[tok * TWOE + EDIM + e];
    y[tok * EDIM + e] = f2bf((acc + uv * De) * em_silu(z));
  };
  if (len == CL) {
    #pragma unroll
    for (int j = 0; j < CL; ++j) step(j);
  } else {
    for (int j = 0; j < len; ++j) step(j);
  }
}

template<int CL>
__global__ __launch_bounds__(256)
void em_scan_out(const float* __restrict__ dtf, const float* __restrict__ dtr,
                 const unsigned short* __restrict__ ubf, const unsigned short* __restrict__ ubr,
                 const float* __restrict__ dblTf, const float* __restrict__ dblTr,
                 const float* __restrict__ xz,
                 const float* __restrict__ Alogf, const float* __restrict__ Alogr,
                 const float* __restrict__ Dpf, const float* __restrict__ Dpr,
                 const float* __restrict__ Hfw, const float* __restrict__ Hrv,
                 unsigned short* __restrict__ ybf, unsigned short* __restrict__ ybr,
                 int L, int nchunks) {
  const int dir = blockIdx.z;
  const int n = blockIdx.y / nchunks;
  const int c = blockIdx.y % nchunks;
  const int tid = threadIdx.x;
  const int e = blockIdx.x * 256 + tid;
  const float* dt = dir ? dtr : dtf;
  const unsigned short* u = dir ? ubr : ubf;
  const float* dblT = dir ? dblTr : dblTf;
  const float* Alog = dir ? Alogr : Alogf;
  const float* Dp = dir ? Dpr : Dpf;
  const float* Hin = dir ? Hrv : Hfw;
  unsigned short* y = dir ? ybr : ybf;
  const int p0 = c * CL;
  const int len = min(CL, L - p0);
  __shared__ __align__(16) float Bs[CL][SDIM];
  __shared__ __align__(16) float Cs[CL][SDIM];
  for (int i = tid; i < CL * 2 * SDIM; i += 256) {
    const int j = i % CL, v = i / CL;
    if (j < len) {
      const int pos = p0 + j;
      const int l = dir ? (L - 1 - pos) : pos;
      const size_t col = (size_t)n * L + l;
      const float val = dblT[(size_t)(RDIM + v) * NTOKS + col]
                      + dblT[(size_t)(64 + RDIM + v) * NTOKS + col];
      if (v < SDIM) Bs[j][v] = val; else Cs[j][v - SDIM] = val;
    }
  }
  __syncthreads();
  float A[SDIM], h[SDIM];
  bool pw = true;
  const size_t base = ((size_t)(n * nchunks + c) * EDIM + e) * SDIM;
  #pragma unroll
  for (int s = 0; s < SDIM; ++s) {
    A[s] = -__expf(Alog[e * SDIM + s]);
    pw = pw && (fabsf(A[s] + (float)(s + 1)) < 1e-3f * (float)(s + 1));
    h[s] = Hin[base + s];
  }
  const float De = Dp[e];
  if (pw) scan_out_core<CL, true>(dt, u, xz, y, Bs, Cs, A, h, De, n, L, p0, len, dir, e);
  else    scan_out_core<CL, false>(dt, u, xz, y, Bs, Cs, A, h, De, n, L, p0, len, dir, e);
}

extern "C" void kernel_launch(void* const* d_in, const int* in_sizes, int n_in,
                              void* d_out, int out_size, void* d_ws, size_t ws_size,
                              hipStream_t stream) {
  const float* x         = (const float*)d_in[0];
  const float* patch_w   = (const float*)d_in[1];
  const float* patch_b   = (const float*)d_in[2];
  const float* cls_tok   = (const float*)d_in[3];
  const float* pos_emb   = (const float*)d_in[4];
  const float* normf     = (const float*)d_in[5];
  const float* sp_conv_w   = (const float*)d_in[6];
  const float* sp_conv_b   = (const float*)d_in[7];
  const float* sp_xproj    = (const float*)d_in[8];
  const float* sp_dtw      = (const float*)d_in[9];
  const float* sp_dtb      = (const float*)d_in[10];
  const float* sp_Alog     = (const float*)d_in[11];
  const float* sp_D        = (const float*)d_in[12];
  const float* sp_conv_w_r = (const float*)d_in[13];
  const float* sp_conv_b_r = (const float*)d_in[14];
  const float* sp_xproj_r  = (const float*)d_in[15];
  const float* sp_dtw_r    = (const float*)d_in[16];
  const float* sp_dtb_r    = (const float*)d_in[17];
  const float* sp_Alog_r   = (const float*)d_in[18];
  const float* sp_D_r      = (const float*)d_in[19];
  const float* tm_conv_w   = (const float*)d_in[20];
  const float* tm_conv_b   = (const float*)d_in[21];
  const float* tm_xproj    = (const float*)d_in[22];
  const float* tm_dtw      = (const float*)d_in[23];
  const float* tm_dtb      = (const float*)d_in[24];
  const float* tm_Alog     = (const float*)d_in[25];
  const float* tm_D        = (const float*)d_in[26];
  const float* sp_norm     = (const float*)d_in[27];
  const float* sp_inproj   = (const float*)d_in[28];
  const float* sp_outproj  = (const float*)d_in[29];
  const float* tm_norm     = (const float*)d_in[30];
  const float* tm_inproj   = (const float*)d_in[31];
  const float* tm_outproj  = (const float*)d_in[32];

  float* ws = (float*)d_ws;
  size_t o = 0;
  float* hidden   = ws + o; o += (size_t)2 * NTOKS * DMODEL;   // 2 K-split slices
  float* hidden2  = hidden + (size_t)NTOKS * DMODEL;
  float* residual = ws + o; o += (size_t)NTOKS * DMODEL;
  float* xz       = ws + o; o += (size_t)NTOKS * TWOE;
  float* dblT_f   = ws + o; o += (size_t)128 * NTOKS;    // 2 K-slices x 64 rows
  float* dblT_r   = ws + o; o += (size_t)128 * NTOKS;
  float* dt_f     = ws + o; o += (size_t)NTOKS * EDIM;
  float* dt_r     = ws + o; o += (size_t)NTOKS * EDIM;
  unsigned short* xn_bf = (unsigned short*)(ws + o); o += (size_t)NTOKS * DMODEL / 2;
  unsigned short* ub_f  = (unsigned short*)(ws + o); o += (size_t)NTOKS * EDIM;      // 2 dirs
  unsigned short* ub_r  = ub_f + (size_t)NTOKS * EDIM;
  unsigned short* yb_f  = (unsigned short*)(ws + o); o += (size_t)NTOKS * EDIM;      // 2 dirs
  unsigned short* yb_r  = yb_f + (size_t)NTOKS * EDIM;

  // ---- bf16 weight caches (converted once per launch) ----
  const size_t n_inproj  = (size_t)NLAYER * TWOE * DMODEL;   // 7.08M each
  const size_t n_outproj = (size_t)NLAYER * DMODEL * EDIM;   // 3.54M each
  const size_t n_xproj   = (size_t)NLAYER * XDIM * EDIM;     // 516K each
  const size_t n_patch   = (size_t)DMODEL * 768;             // 294K
  unsigned short* spin_bf  = (unsigned short*)(ws + o); o += n_inproj / 2;
  unsigned short* tmin_bf  = (unsigned short*)(ws + o); o += n_inproj / 2;
  unsigned short* spout_bf = (unsigned short*)(ws + o); o += n_outproj / 2;
  unsigned short* tmout_bf = (unsigned short*)(ws + o); o += n_outproj / 2;
  unsigned short* spxp_bf  = (unsigned short*)(ws + o); o += n_xproj / 2;
  unsigned short* spxpr_bf = (unsigned short*)(ws + o); o += n_xproj / 2;
  unsigned short* tmxp_bf  = (unsigned short*)(ws + o); o += n_xproj / 2;
  unsigned short* patch_bf = (unsigned short*)(ws + o); o += n_patch / 2;

  // ---- choose scan chunk lengths based on remaining workspace ----
  // per config need: 2 x (sets*EDIM*SDIM) for H + 2 x (sets*EDIM) for dsum
  const size_t avail = (ws_size / sizeof(float) > o) ? (ws_size / sizeof(float) - o) : 0;
  int spCL = 16, tmCL = 8;
  size_t sets = 394;                                   // max(2*197, 16*13)
  auto need = [](size_t s) { return 2 * s * (size_t)EDIM * (SDIM + 1); };
  if (need(sets) > avail) { tmCL = 16; sets = 208; }   // max(2*99, 16*13)
  if (need(sets) > avail) { spCL = 32; sets = 198; }   // original config
  float* scanPs_f = ws + o; o += sets * (size_t)EDIM;
  float* scanPs_r = ws + o; o += sets * (size_t)EDIM;
  float* scanH_f  = ws + o; o += sets * (size_t)EDIM * SDIM;
  float* scanH_r  = ws + o; o += sets * (size_t)EDIM * SDIM;

  unsigned short* im2col_bf = ub_f;            // aliases: unused until first conv
  float* patch_tmp = dt_f;                     // unused until first dtproj

  const int L_sp = 197;
  const int L_tm = 1576;
  const int NC_sp = (L_sp + spCL - 1) / spCL;       // 13 (CL=16) or 7 (CL=32)
  const int NC_tm = (L_tm + tmCL - 1) / tmCL;       // 197 (CL=8) or 99 (CL=16)
  const int MT = (NTOKS + TM - 1) / TM;             // 25
  const int NT64 = (NTOKS + 63) / 64;               // 50
  const int NTC = (NTOKS + CONV_CT - 1) / CONV_CT;  // 197 conv token-chunks
  const int NT16 = NTOKS / DT_TT;                   // 197 dtproj token-tiles

  // -------- weight pre-conversion (8 dispatches, ~140 MB total) --------
  auto cvt = [&](const float* s, unsigned short* d, size_t n) {
    em_f2bf_arr<<<(unsigned)((n / 4 + 255) / 256), 256, 0, stream>>>(s, d, n);
  };
  cvt(sp_inproj, spin_bf, n_inproj);
  cvt(tm_inproj, tmin_bf, n_inproj);
  cvt(sp_outproj, spout_bf, n_outproj);
  cvt(tm_outproj, tmout_bf, n_outproj);
  cvt(sp_xproj, spxp_bf, n_xproj);
  cvt(sp_xproj_r, spxpr_bf, n_xproj);
  cvt(tm_xproj, tmxp_bf, n_xproj);
  cvt(patch_w, patch_bf, n_patch);

  // -------- patch embed: im2col(bf16) + MFMA GEMM + fused epilogue/norm --------
  em_im2col<<<(NPATCH * 768) / 256, 256, 0, stream>>>(x, im2col_bf);
  em_gemm_abf<<<dim3(DMODEL / TN, (NPATCH + TM - 1) / TM, 1), 256, 0, stream>>>(
      im2col_bf, nullptr, patch_bf, patch_tmp, NPATCH, DMODEL, 768, 768);
  em_embed_norm<<<NTOKS, DMODEL, 0, stream>>>(patch_tmp, patch_b, cls_tok, pos_emb,
                                              sp_norm, residual, xn_bf);

  // -------- 12 spatial bimamba blocks: N=16 sequences of L=197 --------
  for (int i = 0; i < NLAYER; ++i) {
    const float* Alf = sp_Alog + (size_t)i * EDIM * SDIM;
    const float* Alr = sp_Alog_r + (size_t)i * EDIM * SDIM;
    em_gemm_abf<<<dim3(TWOE / TN, MT, 1), 256, 0, stream>>>(
        xn_bf, nullptr, spin_bf + (size_t)i * TWOE * DMODEL, xz, NTOKS, TWOE, DMODEL, DMODEL);
    em_conv_silu<<<dim3(EDIM / 256, NTC, 2), 256, 0, stream>>>(
        xz, sp_conv_w + (size_t)i * EDIM * 4, sp_conv_b + (size_t)i * EDIM,
        sp_conv_w_r + (size_t)i * EDIM * 4, sp_conv_b_r + (size_t)i * EDIM,
        ub_f, ub_r, L_sp);
    em_gemm_xpT<<<dim3(NT64, 2, 2), 256, 0, stream>>>(
        ub_f, ub_r, spxp_bf + (size_t)i * XDIM * EDIM, spxpr_bf + (size_t)i * XDIM * EDIM,
        dblT_f, dblT_r);
    em_dtproj<<<dim3(EDIM / 256, NT16, 2), 256, 0, stream>>>(
        dblT_f, dblT_r, sp_dtw + (size_t)i * EDIM * RDIM, sp_dtw_r + (size_t)i * EDIM * RDIM,
        sp_dtb + (size_t)i * EDIM, sp_dtb_r + (size_t)i * EDIM, dt_f, dt_r);
    if (spCL == 16)
      em_scan_sum<16><<<dim3(EDIM / 256, 16 * NC_sp, 2), 256, 0, stream>>>(
          dt_f, dt_r, ub_f, ub_r, dblT_f, dblT_r, Alf, Alr,
          scanPs_f, scanPs_r, scanH_f, scanH_r, L_sp, NC_sp);
    else
      em_scan_sum<32><<<dim3(EDIM / 256, 16 * NC_sp, 2), 256, 0, stream>>>(
          dt_f, dt_r, ub_f, ub_r, dblT_f, dblT_r, Alf, Alr,
          scanPs_f, scanPs_r, scanH_f, scanH_r, L_sp, NC_sp);
    em_scan_combine<<<dim3(16 * EDIM * SDIM / 256, 1, 2), 256, 0, stream>>>(
        scanPs_f, scanPs_r, Alf, Alr, scanH_f, scanH_r, NC_sp);
    if (spCL == 16)
      em_scan_out<16><<<dim3(EDIM / 256, 16 * NC_sp, 2), 256, 0, stream>>>(
          dt_f, dt_r, ub_f, ub_r, dblT_f, dblT_r, xz, Alf, Alr,
          sp_D + (size_t)i * EDIM, sp_D_r + (size_t)i * EDIM,
          scanH_f, scanH_r, yb_f, yb_r, L_sp, NC_sp);
    else
      em_scan_out<32><<<dim3(EDIM / 256, 16 * NC_sp, 2), 256, 0, stream>>>(
          dt_f, dt_r, ub_f, ub_r, dblT_f, dblT_r, xz, Alf, Alr,
          sp_D + (size_t)i * EDIM, sp_D_r + (size_t)i * EDIM,
          scanH_f, scanH_r, yb_f, yb_r, L_sp, NC_sp);
    em_gemm_abf<<<dim3(DMODEL / TN, MT, 2), 256, 0, stream>>>(
        yb_f, yb_r, spout_bf + (size_t)i * DMODEL * EDIM, hidden, NTOKS, DMODEL, EDIM / 2, EDIM);
    const float* next_w = (i < NLAYER - 1) ? sp_norm + (size_t)(i + 1) * DMODEL : tm_norm;
    em_add_rmsnorm<<<NTOKS, DMODEL, 0, stream>>>(hidden, hidden2, residual, residual,
                                                 next_w, nullptr, xn_bf);
  }

  // -------- 12 temporal mamba blocks: N=2 sequences of L=1576 --------
  for (int i = 0; i < NLAYER; ++i) {
    const float* Al = tm_Alog + (size_t)i * EDIM * SDIM;
    em_gemm_abf<<<dim3(TWOE / TN, MT, 1), 256, 0, stream>>>(
        xn_bf, nullptr, tmin_bf + (size_t)i * TWOE * DMODEL, xz, NTOKS, TWOE, DMODEL, DMODEL);
    em_conv_silu<<<dim3(EDIM / 256, NTC, 1), 256, 0, stream>>>(
        xz, tm_conv_w + (size_t)i * EDIM * 4, tm_conv_b + (size_t)i * EDIM,
        tm_conv_w + (size_t)i * EDIM * 4, tm_conv_b + (size_t)i * EDIM,
        ub_f, ub_r, L_tm);
    em_gemm_xpT<<<dim3(NT64, 2, 1), 256, 0, stream>>>(
        ub_f, ub_r, tmxp_bf + (size_t)i * XDIM * EDIM, tmxp_bf + (size_t)i * XDIM * EDIM,
        dblT_f, dblT_r);
    em_dtproj<<<dim3(EDIM / 256, NT16, 1), 256, 0, stream>>>(
        dblT_f, dblT_r, tm_dtw + (size_t)i * EDIM * RDIM, tm_dtw + (size_t)i * EDIM * RDIM,
        tm_dtb + (size_t)i * EDIM, tm_dtb + (size_t)i * EDIM, dt_f, dt_r);
    if (tmCL == 8)
      em_scan_sum<8><<<dim3(EDIM / 256, 2 * NC_tm, 1), 256, 0, stream>>>(
          dt_f, dt_r, ub_f, ub_r, dblT_f, dblT_r, Al, Al,
          scanPs_f, scanPs_r, scanH_f, scanH_r, L_tm, NC_tm);
    else
      em_scan_sum<16><<<dim3(EDIM / 256, 2 * NC_tm, 1), 256, 0, stream>>>(
          dt_f, dt_r, ub_f, ub_r, dblT_f, dblT_r, Al, Al,
          scanPs_f, scanPs_r, scanH_f, scanH_r, L_tm, NC_tm);
    em_scan_combine<<<dim3(2 * EDIM * SDIM / 256, 1, 1), 256, 0, stream>>>(
        scanPs_f, scanPs_r, Al, Al, scanH_f, scanH_r, NC_tm);
    if (tmCL == 8)
      em_scan_out<8><<<dim3(EDIM / 256, 2 * NC_tm, 1), 256, 0, stream>>>(
          dt_f, dt_r, ub_f, ub_r, dblT_f, dblT_r, xz, Al, Al,
          tm_D + (size_t)i * EDIM, tm_D + (size_t)i * EDIM,
          scanH_f, scanH_r, yb_f, yb_r, L_tm, NC_tm);
    else
      em_scan_out<16><<<dim3(EDIM / 256, 2 * NC_tm, 1), 256, 0, stream>>>(
          dt_f, dt_r, ub_f, ub_r, dblT_f, dblT_r, xz, Al, Al,
          tm_D + (size_t)i * EDIM, tm_D + (size_t)i * EDIM,
          scanH_f, scanH_r, yb_f, yb_r, L_tm, NC_tm);
    em_gemm_abf<<<dim3(DMODEL / TN, MT, 2), 256, 0, stream>>>(
        yb_f, nullptr, tmout_bf + (size_t)i * DMODEL * EDIM, hidden, NTOKS, DMODEL, EDIM / 2, EDIM);
    const bool last = (i == NLAYER - 1);
    const float* next_w = last ? normf : tm_norm + (size_t)(i + 1) * DMODEL;
    em_add_rmsnorm<<<NTOKS, DMODEL, 0, stream>>>(hidden, hidden2, residual,
                                                 last ? nullptr : residual,
                                                 next_w, last ? (float*)d_out : nullptr,
                                                 last ? nullptr : xn_bf);
  }
}

// Round 9
// 3199.832 us; speedup vs baseline: 1.1280x; 1.1238x over previous
//
#include <hip/hip_runtime.h>

#define NTOKS 3152      // B*T*P = 2*8*197
#define DMODEL 384
#define EDIM 768
#define TWOE 1536
#define SDIM 16
#define RDIM 24
#define XDIM 56         // R + 2S
#define NLAYER 12
#define NPATCH 3136     // 16 * 196

typedef __attribute__((ext_vector_type(8))) short bf16x8;
typedef __attribute__((ext_vector_type(4))) float f32x4;

__device__ __forceinline__ float em_silu(float v) { return v / (1.f + __expf(-v)); }

__device__ __forceinline__ unsigned short f2bf(float f) {
  union { float f; unsigned int u; } v; v.f = f;
  const unsigned int r = v.u + 0x7fffu + ((v.u >> 16) & 1u);   // RTNE
  return (unsigned short)(r >> 16);
}
__device__ __forceinline__ unsigned int f2bf2(float lo, float hi) {
  return (unsigned int)f2bf(lo) | ((unsigned int)f2bf(hi) << 16);
}
__device__ __forceinline__ float bf2f(unsigned short s) {
  union { unsigned int u; float f; } v; v.u = (unsigned int)s << 16; return v.f;
}
__device__ __forceinline__ float bfbits_lo(unsigned int u) {
  union { unsigned int u; float f; } v; v.u = u << 16; return v.f;
}
__device__ __forceinline__ float bfbits_hi(unsigned int u) {
  union { unsigned int u; float f; } v; v.u = u & 0xffff0000u; return v.f;
}
__device__ __forceinline__ unsigned int addbf2(unsigned int a, unsigned int b) {
  return f2bf2(bfbits_lo(a) + bfbits_lo(b), bfbits_hi(a) + bfbits_hi(b));
}
__device__ __forceinline__ uint4 addbf8(uint4 a, uint4 b) {
  uint4 r;
  r.x = addbf2(a.x, b.x); r.y = addbf2(a.y, b.y);
  r.z = addbf2(a.z, b.z); r.w = addbf2(a.w, b.w);
  return r;
}
// fast softplus: max(a,0) + log(1+exp(-|a|)); native v_exp/v_log, abs err ~1e-6
__device__ __forceinline__ float em_softplus(float a) {
  const float t = __expf(-fabsf(a));
  return fmaxf(a, 0.f) + __logf(1.f + t);
}

// a[s] = q^(s+1) for s=0..15, log-depth product chain (depth 4, 18 muls)
__device__ __forceinline__ void pow_chain16(float q, float* a) {
  const float q2 = q * q, q4 = q2 * q2, q8 = q4 * q4;
  a[0] = q;       a[1] = q2;      a[2] = q2 * q;  a[3] = q4;
  a[4] = q4 * q;  a[5] = q4 * q2; a[6] = q4 * a[2]; a[7] = q8;
  a[8] = q8 * q;  a[9] = q8 * q2; a[10] = q8 * a[2]; a[11] = q8 * q4;
  a[12] = q8 * a[4]; a[13] = q8 * a[5]; a[14] = q8 * a[6]; a[15] = q8 * q8;
}

// ---------------- fp32 -> bf16 weight pre-conversion (n % 4 == 0) ----------------
__global__ __launch_bounds__(256)
void em_f2bf_arr(const float* __restrict__ s, unsigned short* __restrict__ d, size_t n) {
  const size_t i = ((size_t)blockIdx.x * 256 + threadIdx.x) * 4;
  if (i < n) {
    const float4 v = *reinterpret_cast<const float4*>(s + i);
    uint2 pk;
    pk.x = f2bf2(v.x, v.y); pk.y = f2bf2(v.z, v.w);
    *reinterpret_cast<uint2*>(d + i) = pk;
  }
}

// ---------------- im2col (bf16 out) for patch embed: col[3136][768] ----------------
__global__ __launch_bounds__(256)
void em_im2col(const float* __restrict__ x, unsigned short* __restrict__ col) {
  const int g = blockIdx.x * 256 + threadIdx.x;   // pr*768 + cc
  const int pr = g / 768;
  const int cc = g - pr * 768;
  const int np = pr % 196;
  const int bt = pr / 196;
  const int t = bt & 7, b = bt >> 3;
  const int hp = np / 14, wp = np - hp * 14;
  const int c = cc >> 8;
  const int rem = cc & 255;
  const int ph = rem >> 4, pw = rem & 15;
  col[g] = f2bf(x[(((size_t)(b * 3 + c) * 8 + t) * 224 + (hp * 16 + ph)) * 224 + (wp * 16 + pw)]);
}

// -------- patch embed epilogue fused with first residual+RMSNorm --------
__global__ __launch_bounds__(DMODEL)
void em_embed_norm(const float* __restrict__ tmpP, const float* __restrict__ pb,
                   const float* __restrict__ cls, const float* __restrict__ pos,
                   const float* __restrict__ w,
                   float* __restrict__ residual, unsigned short* __restrict__ xn_bf) {
  const int tok = blockIdx.x;
  const int d = threadIdx.x;
  const int p = tok % 197;
  const int bt = tok / 197;
  const int t = bt & 7;
  float v;
  if (p == 0) {
    v = cls[d] + pos[d];
  } else {
    const int np = p - 1;
    const float div = powf(10000.f, (float)(d & ~1) * (1.f / 384.f));
    const float ang = (float)t / div;
    const float enc = (d & 1) ? cosf(ang) : sinf(ang);
    v = tmpP[((size_t)bt * 196 + np) * DMODEL + d] + pb[d] + pos[(size_t)p * DMODEL + d] + enc;
  }
  const size_t idx = (size_t)tok * DMODEL + d;
  residual[idx] = v;
  float ss = v * v;
  #pragma unroll
  for (int off = 32; off; off >>= 1) ss += __shfl_xor(ss, off, 64);
  __shared__ float red[6];
  if ((d & 63) == 0) red[d >> 6] = ss;
  __syncthreads();
  float tot = 0.f;
  #pragma unroll
  for (int i = 0; i < 6; ++i) tot += red[i];
  const float scale = rsqrtf(tot * (1.f / 384.f) + 1e-5f);
  xn_bf[idx] = f2bf(v * scale * w[d]);
}

// ------- residual add (+ optional K-split partial) + RMSNorm; bf16 (layers) / fp32 (final) -----
__global__ __launch_bounds__(DMODEL)
void em_add_rmsnorm(const float* __restrict__ hidden, const float* __restrict__ hidden2,
                    const float* __restrict__ res_in,
                    float* __restrict__ res_out, const float* __restrict__ w,
                    float* __restrict__ out, unsigned short* __restrict__ out_bf) {
  const int tok = blockIdx.x;
  const int d = threadIdx.x;
  const size_t idx = (size_t)tok * DMODEL + d;
  float v = hidden[idx] + res_in[idx];
  if (hidden2) v += hidden2[idx];
  if (res_out) res_out[idx] = v;
  float ss = v * v;
  #pragma unroll
  for (int off = 32; off; off >>= 1) ss += __shfl_xor(ss, off, 64);
  __shared__ float red[6];
  if ((d & 63) == 0) red[d >> 6] = ss;
  __syncthreads();
  float tot = 0.f;
  #pragma unroll
  for (int i = 0; i < 6; ++i) tot += red[i];
  const float scale = rsqrtf(tot * (1.f / 384.f) + 1e-5f);
  const float r = v * scale * w[d];
  if (out_bf) out_bf[idx] = f2bf(r);
  else out[idx] = r;
}

// ====== MFMA GEMM, bf16 A (+A2) and bf16 W, LDS ping-pong double-buffer, optional K-split ======
// grid: (N/TN, ceil(M/TM), nks); K = per-slice length, KS = full row stride.
#define TM 128
#define TN 64
#define LDT 40   // ushorts per LDS row (32 + 8 pad)
__global__ __launch_bounds__(256)
void em_gemm_abf(const unsigned short* __restrict__ A, const unsigned short* __restrict__ A2,
                 const unsigned short* __restrict__ W, float* __restrict__ C,
                 int M, int N, int K, int KS) {
  __shared__ unsigned short As[2][TM * LDT];
  __shared__ unsigned short Bs[2][TN * LDT];
  const int tid = threadIdx.x;
  const int bm = blockIdx.y * TM;
  const int bn = blockIdx.x * TN;
  const int kk0 = blockIdx.z * K;
  const int kkend = kk0 + K;
  const int wave = tid >> 6, lane = tid & 63;
  const int wm = (wave >> 1) * 64, wn = (wave & 1) * 32;
  const int mq = lane & 15, quad = lane >> 4;
  f32x4 acc[4][2] = {};
  const int ar = tid >> 1;
  const int ah = (tid & 1) * 16;
  const int br = tid >> 2;
  const int bk = (tid & 3) * 8;
  const int arow = bm + ar;

  uint4 a0, a1, b0;
  auto load_tile = [&](int kk) {
    a0 = {0, 0, 0, 0}; a1 = {0, 0, 0, 0};
    if (arow < M) {
      const uint4* pa = reinterpret_cast<const uint4*>(A + (size_t)arow * KS + kk + ah);
      a0 = pa[0]; a1 = pa[1];
      if (A2) {
        const uint4* pb = reinterpret_cast<const uint4*>(A2 + (size_t)arow * KS + kk + ah);
        a0 = addbf8(a0, pb[0]); a1 = addbf8(a1, pb[1]);
      }
    }
    b0 = *reinterpret_cast<const uint4*>(W + (size_t)(bn + br) * KS + kk + bk);
  };
  auto store_tile = [&](int buf) {
    uint4* dst = reinterpret_cast<uint4*>(&As[buf][ar * LDT + ah]);
    dst[0] = a0; dst[1] = a1;
    *reinterpret_cast<uint4*>(&Bs[buf][br * LDT + bk]) = b0;
  };

  load_tile(kk0);
  store_tile(0);
  __syncthreads();
  int cur = 0;
  for (int kk = kk0; kk < kkend; kk += 32) {
    const bool have = (kk + 32) < kkend;
    if (have) load_tile(kk + 32);
    bf16x8 bfr[2];
    #pragma unroll
    for (int j = 0; j < 2; ++j)
      bfr[j] = *reinterpret_cast<const bf16x8*>(&Bs[cur][(wn + j * 16 + mq) * LDT + quad * 8]);
    #pragma unroll
    for (int i = 0; i < 4; ++i) {
      const bf16x8 afr = *reinterpret_cast<const bf16x8*>(&As[cur][(wm + i * 16 + mq) * LDT + quad * 8]);
      acc[i][0] = __builtin_amdgcn_mfma_f32_16x16x32_bf16(afr, bfr[0], acc[i][0], 0, 0, 0);
      acc[i][1] = __builtin_amdgcn_mfma_f32_16x16x32_bf16(afr, bfr[1], acc[i][1], 0, 0, 0);
    }
    if (have) {
      store_tile(cur ^ 1);
      __syncthreads();
      cur ^= 1;
    }
  }
  float* Cz = C + (size_t)blockIdx.z * M * N;
  #pragma unroll
  for (int i = 0; i < 4; ++i) {
    const int mbase = bm + wm + i * 16 + quad * 4;
    #pragma unroll
    for (int j = 0; j < 2; ++j) {
      const int col = bn + wn + j * 16 + mq;
      #pragma unroll
      for (int p = 0; p < 4; ++p) {
        const int m = mbase + p;
        if (m < M) Cz[(size_t)m * N + col] = acc[i][j][p];
      }
    }
  }
}

// ===== transposed xproj GEMM (bf16 W), K-split x2, LDS ping-pong double-buffer:
//       dblT[slice][64][NTOKS] = xp[56, Kslice] @ u[:, Kslice]^T ; consumers sum slices =====
// grid: (ceil(NTOKS/64), 2, dirs)
__global__ __launch_bounds__(256)
void em_gemm_xpT(const unsigned short* __restrict__ ubf, const unsigned short* __restrict__ ubr,
                 const unsigned short* __restrict__ xpf, const unsigned short* __restrict__ xpr,
                 float* __restrict__ dblTf, float* __restrict__ dblTr) {
  const int dir = blockIdx.z;
  const int ks = blockIdx.y;                // K slice: 0..1
  const unsigned short* U = dir ? ubr : ubf;
  const unsigned short* W = dir ? xpr : xpf;
  float* C = dir ? dblTr : dblTf;
  __shared__ unsigned short As[2][64 * LDT];   // xp tile (56 real rows)
  __shared__ unsigned short Bs[2][64 * LDT];   // u tile (64 tokens)
  const int tid = threadIdx.x;
  const int bn = blockIdx.x * 64;           // token base
  const int wave = tid >> 6, lane = tid & 63;
  const int wm = wave * 16;
  const int mq = lane & 15, quad = lane >> 4;
  f32x4 acc[4] = {};
  const int sr = tid >> 2;
  const int sq = (tid & 3) * 8;
  const int k0 = ks * (EDIM / 2), k1 = k0 + EDIM / 2;
  const int btok = bn + sr;

  uint4 wa, ub;
  auto load_tile = [&](int kk) {
    wa = {0, 0, 0, 0}; ub = {0, 0, 0, 0};
    if (sr < XDIM)
      wa = *reinterpret_cast<const uint4*>(W + (size_t)sr * EDIM + kk + sq);
    if (btok < NTOKS)
      ub = *reinterpret_cast<const uint4*>(U + (size_t)btok * EDIM + kk + sq);
  };
  auto store_tile = [&](int buf) {
    *reinterpret_cast<uint4*>(&As[buf][sr * LDT + sq]) = wa;
    *reinterpret_cast<uint4*>(&Bs[buf][sr * LDT + sq]) = ub;
  };

  load_tile(k0);
  store_tile(0);
  __syncthreads();
  int cur = 0;
  for (int kk = k0; kk < k1; kk += 32) {
    const bool have = (kk + 32) < k1;
    if (have) load_tile(kk + 32);
    const bf16x8 afr = *reinterpret_cast<const bf16x8*>(&As[cur][(wm + mq) * LDT + quad * 8]);
    #pragma unroll
    for (int j = 0; j < 4; ++j) {
      const bf16x8 bfr = *reinterpret_cast<const bf16x8*>(&Bs[cur][(j * 16 + mq) * LDT + quad * 8]);
      acc[j] = __builtin_amdgcn_mfma_f32_16x16x32_bf16(afr, bfr, acc[j], 0, 0, 0);
    }
    if (have) {
      store_tile(cur ^ 1);
      __syncthreads();
      cur ^= 1;
    }
  }
  #pragma unroll
  for (int j = 0; j < 4; ++j) {
    const int tok = bn + j * 16 + mq;
    if (tok < NTOKS) {
      #pragma unroll
      for (int p = 0; p < 4; ++p) {
        const int m = wm + quad * 4 + p;
        C[(size_t)(ks * 64 + m) * NTOKS + tok] = acc[j][p];
      }
    }
  }
}

// ---------------- dt projection: dt[tok][e] = softplus(r(tok)·dtw[e] + dtb[e]) ----------------
// grid: (EDIM/256, NTOKS/16, dirs)
#define DT_TT 16
__global__ __launch_bounds__(256)
void em_dtproj(const float* __restrict__ dblTf, const float* __restrict__ dblTr,
               const float* __restrict__ dtwf, const float* __restrict__ dtwr,
               const float* __restrict__ dtbf, const float* __restrict__ dtbr,
               float* __restrict__ dtf, float* __restrict__ dtr) {
  const int e = blockIdx.x * 256 + threadIdx.x;
  const int t0 = blockIdx.y * DT_TT;
  const int dir = blockIdx.z;
  const float* dblT = dir ? dblTr : dblTf;
  const float* dtw = dir ? dtwr : dtwf;
  const float* dtb = dir ? dtbr : dtbf;
  float* dto = dir ? dtr : dtf;
  __shared__ float r[DT_TT][RDIM + 1];   // +1 pad: odd stride, conflict-free
  for (int i = threadIdx.x; i < DT_TT * RDIM; i += 256) {   // 384 entries, 256 threads
    const int tt = i & (DT_TT - 1);
    const int j = i >> 4;
    const int tok = t0 + tt;                                // NTOKS % 16 == 0: always valid
    r[tt][j] = dblT[(size_t)j * NTOKS + tok] + dblT[(size_t)(64 + j) * NTOKS + tok];
  }
  __syncthreads();
  const float4* wp = reinterpret_cast<const float4*>(dtw + (size_t)e * RDIM);  // 96B aligned
  float w[RDIM];
  #pragma unroll
  for (int q = 0; q < 6; ++q) {
    const float4 v = wp[q];
    w[q * 4 + 0] = v.x; w[q * 4 + 1] = v.y; w[q * 4 + 2] = v.z; w[q * 4 + 3] = v.w;
  }
  const float b = dtb[e];
  float* o = dto + (size_t)t0 * EDIM + e;
  #pragma unroll 4
  for (int tt = 0; tt < DT_TT; ++tt) {
    float a = b;
    #pragma unroll
    for (int j = 0; j < RDIM; ++j) a += r[tt][j] * w[j];   // LDS broadcast reads
    o[(size_t)tt * EDIM] = em_softplus(a);
  }
}

// ---------------- depthwise conv + SiLU; sliding register window, 16 tokens/thread ------------
// grid: (EDIM/256, ceil(NTOKS/16), dirs)
#define CONV_CT 16
__global__ __launch_bounds__(256)
void em_conv_silu(const float* __restrict__ xz,
                  const float* __restrict__ cwf, const float* __restrict__ cbf,
                  const float* __restrict__ cwr, const float* __restrict__ cbr,
                  unsigned short* __restrict__ ubf, unsigned short* __restrict__ ubr, int L) {
  const int e = blockIdx.x * 256 + threadIdx.x;
  const int t0 = blockIdx.y * CONV_CT;
  const int dir = blockIdx.z;
  const float* cw = dir ? cwr : cwf;
  const float* cb = dir ? cbr : cbf;
  unsigned short* out = dir ? ubr : ubf;
  const float4 wv = *reinterpret_cast<const float4*>(cw + e * 4);
  const float w0 = wv.x, w1 = wv.y, w2 = wv.z, w3 = wv.w;
  const float bv = cb[e];
  const float* xcol = xz + e;               // u-half column of xz, stride TWOE per token
  int l = t0 % L;
  if (dir == 0) {
    float xm1 = (l >= 1) ? xcol[(size_t)(t0 - 1) * TWOE] : 0.f;
    float xm2 = (l >= 2) ? xcol[(size_t)(t0 - 2) * TWOE] : 0.f;
    float xm3 = (l >= 3) ? xcol[(size_t)(t0 - 3) * TWOE] : 0.f;
    for (int tt = 0; tt < CONV_CT; ++tt) {
      const int tok = t0 + tt;
      if (tok >= NTOKS) break;
      const float xc = xcol[(size_t)tok * TWOE];
      float acc = bv + xc * w3;
      if (l >= 1) acc += xm1 * w2;
      if (l >= 2) acc += xm2 * w1;
      if (l >= 3) acc += xm3 * w0;
      out[(size_t)tok * EDIM + e] = f2bf(em_silu(acc));
      xm3 = xm2; xm2 = xm1; xm1 = xc;
      if (++l == L) l = 0;                  // new sequence: guards zero stale window
    }
  } else {
    float xc  = xcol[(size_t)t0 * TWOE];
    float xp1 = (t0 + 1 < NTOKS) ? xcol[(size_t)(t0 + 1) * TWOE] : 0.f;
    float xp2 = (t0 + 2 < NTOKS) ? xcol[(size_t)(t0 + 2) * TWOE] : 0.f;
    for (int tt = 0; tt < CONV_CT; ++tt) {
      const int tok = t0 + tt;
      if (tok >= NTOKS) break;
      const float xp3 = (tok + 3 < NTOKS) ? xcol[(size_t)(tok + 3) * TWOE] : 0.f;
      float acc = bv + xc * w3;
      if (l + 1 < L) acc += xp1 * w2;
      if (l + 2 < L) acc += xp2 * w1;
      if (l + 3 < L) acc += xp3 * w0;
      out[(size_t)tok * EDIM + e] = f2bf(em_silu(acc));
      xc = xp1; xp1 = xp2; xp2 = xp3;
      if (++l == L) l = 0;
    }
  }
}

// ================= chunked scan (templated chunk length) =================
// PW path: A[s] == -(s+1) (verified at runtime) -> exp(dtv*A[s]) = q^(s+1), q=exp(-dtv).
template<int CL, bool PW>
__device__ __forceinline__ void scan_sum_core(
    const float* __restrict__ dt, const unsigned short* __restrict__ u,
    const float (* __restrict__ Bs)[SDIM], const float* __restrict__ A,
    float* __restrict__ h, float* __restrict__ Pp, float& dsum,
    int n, int L, int p0, int len, int dir, int e) {
  auto step = [&](int j) {
    const int pos = p0 + j;
    const int l = dir ? (L - 1 - pos) : pos;
    const size_t tok = (size_t)n * L + l;
    const float dtv = dt[tok * EDIM + e];
    const float dtu = dtv * bf2f(u[tok * EDIM + e]);
    float a[SDIM];
    if (PW) {
      dsum += dtv;
      pow_chain16(__expf(-dtv), a);
    } else {
      #pragma unroll
      for (int s = 0; s < SDIM; ++s) a[s] = __expf(dtv * A[s]);
    }
    const float4* b4 = reinterpret_cast<const float4*>(Bs[j]);
    float bb[SDIM];
    #pragma unroll
    for (int q = 0; q < 4; ++q) {
      const float4 v = b4[q];
      bb[4*q] = v.x; bb[4*q+1] = v.y; bb[4*q+2] = v.z; bb[4*q+3] = v.w;
    }
    #pragma unroll
    for (int s = 0; s < SDIM; ++s) {
      h[s] = a[s] * h[s] + dtu * bb[s];
      if (!PW) Pp[s] *= a[s];
    }
  };
  if (len == CL) {
    #pragma unroll
    for (int j = 0; j < CL; ++j) step(j);
  } else {
    for (int j = 0; j < len; ++j) step(j);
  }
}

template<int CL>
__global__ __launch_bounds__(256)
void em_scan_sum(const float* __restrict__ dtf, const float* __restrict__ dtr,
                 const unsigned short* __restrict__ ubf, const unsigned short* __restrict__ ubr,
                 const float* __restrict__ dblTf, const float* __restrict__ dblTr,
                 const float* __restrict__ Alogf, const float* __restrict__ Alogr,
                 float* __restrict__ Pfw, float* __restrict__ Prv,
                 float* __restrict__ Hfw, float* __restrict__ Hrv,
                 int L, int nchunks) {
  const int dir = blockIdx.z;
  const int n = blockIdx.y / nchunks;
  const int c = blockIdx.y % nchunks;
  const int tid = threadIdx.x;
  const int e = blockIdx.x * 256 + tid;
  const float* dt = dir ? dtr : dtf;
  const unsigned short* u = dir ? ubr : ubf;
  const float* dblT = dir ? dblTr : dblTf;
  const float* Alog = dir ? Alogr : Alogf;
  float* P = dir ? Prv : Pfw;
  float* H = dir ? Hrv : Hfw;
  const int p0 = c * CL;
  const int len = min(CL, L - p0);
  __shared__ __align__(16) float Bs[CL][SDIM];
  for (int i = tid; i < CL * SDIM; i += 256) {
    const int j = i % CL, s = i / CL;
    if (j < len) {
      const int pos = p0 + j;
      const int l = dir ? (L - 1 - pos) : pos;
      const size_t col = (size_t)n * L + l;
      Bs[j][s] = dblT[(size_t)(RDIM + s) * NTOKS + col]
               + dblT[(size_t)(64 + RDIM + s) * NTOKS + col];
    }
  }
  __syncthreads();
  float A[SDIM], h[SDIM], Pp[SDIM];
  bool pw = true;
  #pragma unroll
  for (int s = 0; s < SDIM; ++s) {
    A[s] = -__expf(Alog[e * SDIM + s]);
    pw = pw && (fabsf(A[s] + (float)(s + 1)) < 1e-3f * (float)(s + 1));
    h[s] = 0.f;
  }
  float dsum = 0.f;
  if (pw) {
    scan_sum_core<CL, true>(dt, u, Bs, A, h, Pp, dsum, n, L, p0, len, dir, e);
    pow_chain16(__expf(-dsum), Pp);
  } else {
    #pragma unroll
    for (int s = 0; s < SDIM; ++s) Pp[s] = 1.f;
    scan_sum_core<CL, false>(dt, u, Bs, A, h, Pp, dsum, n, L, p0, len, dir, e);
  }
  const size_t base = ((size_t)(n * nchunks + c) * EDIM + e) * SDIM;
  #pragma unroll
  for (int s = 0; s < SDIM; ++s) { P[base + s] = Pp[s]; H[base + s] = h[s]; }
}

__global__ __launch_bounds__(256)
void em_scan_combine(const float* __restrict__ Pfw, const float* __restrict__ Prv,
                     float* __restrict__ Hfw, float* __restrict__ Hrv, int nchunks) {
  const int dir = blockIdx.z;
  const int idx = blockIdx.x * 256 + threadIdx.x;
  const int n = idx / (EDIM * SDIM);
  const int r = idx % (EDIM * SDIM);
  const float* P = dir ? Prv : Pfw;
  float* H = dir ? Hrv : Hfw;
  const size_t st = (size_t)EDIM * SDIM;
  size_t b = (size_t)n * nchunks * st + r;
  float h = 0.f;
  for (int c0 = 0; c0 < nchunks; c0 += 8) {
    float pv[8], hf[8];
    #pragma unroll
    for (int q = 0; q < 8; ++q)
      if (c0 + q < nchunks) { pv[q] = P[b + (size_t)q * st]; hf[q] = H[b + (size_t)q * st]; }
    #pragma unroll
    for (int q = 0; q < 8; ++q)
      if (c0 + q < nchunks) { H[b + (size_t)q * st] = h; h = pv[q] * h + hf[q]; }
    b += 8 * st;
  }
}

template<int CL, bool PW>
__device__ __forceinline__ void scan_out_core(
    const float* __restrict__ dt, const unsigned short* __restrict__ u,
    const float* __restrict__ xz, unsigned short* __restrict__ y,
    const float (* __restrict__ Bs)[SDIM], const float (* __restrict__ Cs)[SDIM],
    const float* __restrict__ A, float* __restrict__ h, float De,
    int n, int L, int p0, int len, int dir, int e) {
  auto step = [&](int j) {
    const int pos = p0 + j;
    const int l = dir ? (L - 1 - pos) : pos;
    const size_t tok = (size_t)n * L + l;
    const float dtv = dt[tok * EDIM + e];
    const float uv = bf2f(u[tok * EDIM + e]);
    const float dtu = dtv * uv;
    float a[SDIM];
    if (PW) {
      pow_chain16(__expf(-dtv), a);
    } else {
      #pragma unroll
      for (int s = 0; s < SDIM; ++s) a[s] = __expf(dtv * A[s]);
    }
    const float4* b4 = reinterpret_cast<const float4*>(Bs[j]);
    const float4* c4 = reinterpret_cast<const float4*>(Cs[j]);
    float bb[SDIM], cc[SDIM];
    #pragma unroll
    for (int q = 0; q < 4; ++q) {
      const float4 vb = b4[q], vc = c4[q];
      bb[4*q] = vb.x; bb[4*q+1] = vb.y; bb[4*q+2] = vb.z; bb[4*q+3] = vb.w;
      cc[4*q] = vc.x; cc[4*q+1] = vc.y; cc[4*q+2] = vc.z; cc[4*q+3] = vc.w;
    }
    float acc = 0.f;
    #pragma unroll
    for (int s = 0; s < SDIM; ++s) {
      h[s] = a[s] * h[s] + dtu * bb[s];
      acc += h[s] * cc[s];
    }
    const float z = xz[tok * TWOE + EDIM + e];
    y[tok * EDIM + e] = f2bf((acc + uv * De) * em_silu(z));
  };
  if (len == CL) {
    #pragma unroll
    for (int j = 0; j < CL; ++j) step(j);
  } else {
    for (int j = 0; j < len; ++j) step(j);
  }
}

template<int CL>
__global__ __launch_bounds__(256)
void em_scan_out(const float* __restrict__ dtf, const float* __restrict__ dtr,
                 const unsigned short* __restrict__ ubf, const unsigned short* __restrict__ ubr,
                 const float* __restrict__ dblTf, const float* __restrict__ dblTr,
                 const float* __restrict__ xz,
                 const float* __restrict__ Alogf, const float* __restrict__ Alogr,
                 const float* __restrict__ Dpf, const float* __restrict__ Dpr,
                 const float* __restrict__ Hfw, const float* __restrict__ Hrv,
                 unsigned short* __restrict__ ybf, unsigned short* __restrict__ ybr,
                 int L, int nchunks) {
  const int dir = blockIdx.z;
  const int n = blockIdx.y / nchunks;
  const int c = blockIdx.y % nchunks;
  const int tid = threadIdx.x;
  const int e = blockIdx.x * 256 + tid;
  const float* dt = dir ? dtr : dtf;
  const unsigned short* u = dir ? ubr : ubf;
  const float* dblT = dir ? dblTr : dblTf;
  const float* Alog = dir ? Alogr : Alogf;
  const float* Dp = dir ? Dpr : Dpf;
  const float* Hin = dir ? Hrv : Hfw;
  unsigned short* y = dir ? ybr : ybf;
  const int p0 = c * CL;
  const int len = min(CL, L - p0);
  __shared__ __align__(16) float Bs[CL][SDIM];
  __shared__ __align__(16) float Cs[CL][SDIM];
  for (int i = tid; i < CL * 2 * SDIM; i += 256) {
    const int j = i % CL, v = i / CL;
    if (j < len) {
      const int pos = p0 + j;
      const int l = dir ? (L - 1 - pos) : pos;
      const size_t col = (size_t)n * L + l;
      const float val = dblT[(size_t)(RDIM + v) * NTOKS + col]
                      + dblT[(size_t)(64 + RDIM + v) * NTOKS + col];
      if (v < SDIM) Bs[j][v] = val; else Cs[j][v - SDIM] = val;
    }
  }
  __syncthreads();
  float A[SDIM], h[SDIM];
  bool pw = true;
  const size_t base = ((size_t)(n * nchunks + c) * EDIM + e) * SDIM;
  #pragma unroll
  for (int s = 0; s < SDIM; ++s) {
    A[s] = -__expf(Alog[e * SDIM + s]);
    pw = pw && (fabsf(A[s] + (float)(s + 1)) < 1e-3f * (float)(s + 1));
    h[s] = Hin[base + s];
  }
  const float De = Dp[e];
  if (pw) scan_out_core<CL, true>(dt, u, xz, y, Bs, Cs, A, h, De, n, L, p0, len, dir, e);
  else    scan_out_core<CL, false>(dt, u, xz, y, Bs, Cs, A, h, De, n, L, p0, len, dir, e);
}

extern "C" void kernel_launch(void* const* d_in, const int* in_sizes, int n_in,
                              void* d_out, int out_size, void* d_ws, size_t ws_size,
                              hipStream_t stream) {
  const float* x         = (const float*)d_in[0];
  const float* patch_w   = (const float*)d_in[1];
  const float* patch_b   = (const float*)d_in[2];
  const float* cls_tok   = (const float*)d_in[3];
  const float* pos_emb   = (const float*)d_in[4];
  const float* normf     = (const float*)d_in[5];
  const float* sp_conv_w   = (const float*)d_in[6];
  const float* sp_conv_b   = (const float*)d_in[7];
  const float* sp_xproj    = (const float*)d_in[8];
  const float* sp_dtw      = (const float*)d_in[9];
  const float* sp_dtb      = (const float*)d_in[10];
  const float* sp_Alog     = (const float*)d_in[11];
  const float* sp_D        = (const float*)d_in[12];
  const float* sp_conv_w_r = (const float*)d_in[13];
  const float* sp_conv_b_r = (const float*)d_in[14];
  const float* sp_xproj_r  = (const float*)d_in[15];
  const float* sp_dtw_r    = (const float*)d_in[16];
  const float* sp_dtb_r    = (const float*)d_in[17];
  const float* sp_Alog_r   = (const float*)d_in[18];
  const float* sp_D_r      = (const float*)d_in[19];
  const float* tm_conv_w   = (const float*)d_in[20];
  const float* tm_conv_b   = (const float*)d_in[21];
  const float* tm_xproj    = (const float*)d_in[22];
  const float* tm_dtw      = (const float*)d_in[23];
  const float* tm_dtb      = (const float*)d_in[24];
  const float* tm_Alog     = (const float*)d_in[25];
  const float* tm_D        = (const float*)d_in[26];
  const float* sp_norm     = (const float*)d_in[27];
  const float* sp_inproj   = (const float*)d_in[28];
  const float* sp_outproj  = (const float*)d_in[29];
  const float* tm_norm     = (const float*)d_in[30];
  const float* tm_inproj   = (const float*)d_in[31];
  const float* tm_outproj  = (const float*)d_in[32];

  float* ws = (float*)d_ws;
  size_t o = 0;
  float* hidden   = ws + o; o += (size_t)2 * NTOKS * DMODEL;   // 2 K-split slices
  float* hidden2  = hidden + (size_t)NTOKS * DMODEL;
  float* residual = ws + o; o += (size_t)NTOKS * DMODEL;
  float* xz       = ws + o; o += (size_t)NTOKS * TWOE;
  float* dblT_f   = ws + o; o += (size_t)128 * NTOKS;    // 2 K-slices x 64 rows
  float* dblT_r   = ws + o; o += (size_t)128 * NTOKS;
  float* dt_f     = ws + o; o += (size_t)NTOKS * EDIM;
  float* dt_r     = ws + o; o += (size_t)NTOKS * EDIM;
  unsigned short* xn_bf = (unsigned short*)(ws + o); o += (size_t)NTOKS * DMODEL / 2;
  unsigned short* ub_f  = (unsigned short*)(ws + o); o += (size_t)NTOKS * EDIM;      // 2 dirs
  unsigned short* ub_r  = ub_f + (size_t)NTOKS * EDIM;
  unsigned short* yb_f  = (unsigned short*)(ws + o); o += (size_t)NTOKS * EDIM;      // 2 dirs
  unsigned short* yb_r  = yb_f + (size_t)NTOKS * EDIM;

  // ---- bf16 weight caches (converted once per launch) ----
  const size_t n_inproj  = (size_t)NLAYER * TWOE * DMODEL;   // 7.08M each
  const size_t n_outproj = (size_t)NLAYER * DMODEL * EDIM;   // 3.54M each
  const size_t n_xproj   = (size_t)NLAYER * XDIM * EDIM;     // 516K each
  const size_t n_patch   = (size_t)DMODEL * 768;             // 294K
  unsigned short* spin_bf  = (unsigned short*)(ws + o); o += n_inproj / 2;
  unsigned short* tmin_bf  = (unsigned short*)(ws + o); o += n_inproj / 2;
  unsigned short* spout_bf = (unsigned short*)(ws + o); o += n_outproj / 2;
  unsigned short* tmout_bf = (unsigned short*)(ws + o); o += n_outproj / 2;
  unsigned short* spxp_bf  = (unsigned short*)(ws + o); o += n_xproj / 2;
  unsigned short* spxpr_bf = (unsigned short*)(ws + o); o += n_xproj / 2;
  unsigned short* tmxp_bf  = (unsigned short*)(ws + o); o += n_xproj / 2;
  unsigned short* patch_bf = (unsigned short*)(ws + o); o += n_patch / 2;

  // ---- choose scan chunk lengths based on remaining workspace ----
  const size_t avail = (ws_size / sizeof(float) > o) ? (ws_size / sizeof(float) - o) : 0;
  int spCL = 16, tmCL = 8;
  size_t sets = 394;                                   // max(2*197, 16*13)
  if (4 * sets * (size_t)(EDIM * SDIM) > avail) { tmCL = 16; sets = 208; }  // max(2*99, 16*13)
  if (4 * sets * (size_t)(EDIM * SDIM) > avail) { spCL = 32; sets = 198; }  // original config
  const size_t sum_elems = sets * (size_t)EDIM * SDIM;
  float* scanP_f  = ws + o; o += sum_elems;
  float* scanP_r  = ws + o; o += sum_elems;
  float* scanH_f  = ws + o; o += sum_elems;
  float* scanH_r  = ws + o; o += sum_elems;

  unsigned short* im2col_bf = ub_f;            // aliases: unused until first conv
  float* patch_tmp = dt_f;                     // unused until first dtproj

  const int L_sp = 197;
  const int L_tm = 1576;
  const int NC_sp = (L_sp + spCL - 1) / spCL;       // 13 (CL=16) or 7 (CL=32)
  const int NC_tm = (L_tm + tmCL - 1) / tmCL;       // 197 (CL=8) or 99 (CL=16)
  const int MT = (NTOKS + TM - 1) / TM;             // 25
  const int NT64 = (NTOKS + 63) / 64;               // 50
  const int NTC = (NTOKS + CONV_CT - 1) / CONV_CT;  // 197 conv token-chunks
  const int NT16 = NTOKS / DT_TT;                   // 197 dtproj token-tiles

  // -------- weight pre-conversion (8 dispatches, ~140 MB total) --------
  auto cvt = [&](const float* s, unsigned short* d, size_t n) {
    em_f2bf_arr<<<(unsigned)((n / 4 + 255) / 256), 256, 0, stream>>>(s, d, n);
  };
  cvt(sp_inproj, spin_bf, n_inproj);
  cvt(tm_inproj, tmin_bf, n_inproj);
  cvt(sp_outproj, spout_bf, n_outproj);
  cvt(tm_outproj, tmout_bf, n_outproj);
  cvt(sp_xproj, spxp_bf, n_xproj);
  cvt(sp_xproj_r, spxpr_bf, n_xproj);
  cvt(tm_xproj, tmxp_bf, n_xproj);
  cvt(patch_w, patch_bf, n_patch);

  // -------- patch embed: im2col(bf16) + MFMA GEMM + fused epilogue/norm --------
  em_im2col<<<(NPATCH * 768) / 256, 256, 0, stream>>>(x, im2col_bf);
  em_gemm_abf<<<dim3(DMODEL / TN, (NPATCH + TM - 1) / TM, 1), 256, 0, stream>>>(
      im2col_bf, nullptr, patch_bf, patch_tmp, NPATCH, DMODEL, 768, 768);
  em_embed_norm<<<NTOKS, DMODEL, 0, stream>>>(patch_tmp, patch_b, cls_tok, pos_emb,
                                              sp_norm, residual, xn_bf);

  // -------- 12 spatial bimamba blocks: N=16 sequences of L=197 --------
  for (int i = 0; i < NLAYER; ++i) {
    const float* Alf = sp_Alog + (size_t)i * EDIM * SDIM;
    const float* Alr = sp_Alog_r + (size_t)i * EDIM * SDIM;
    em_gemm_abf<<<dim3(TWOE / TN, MT, 1), 256, 0, stream>>>(
        xn_bf, nullptr, spin_bf + (size_t)i * TWOE * DMODEL, xz, NTOKS, TWOE, DMODEL, DMODEL);
    em_conv_silu<<<dim3(EDIM / 256, NTC, 2), 256, 0, stream>>>(
        xz, sp_conv_w + (size_t)i * EDIM * 4, sp_conv_b + (size_t)i * EDIM,
        sp_conv_w_r + (size_t)i * EDIM * 4, sp_conv_b_r + (size_t)i * EDIM,
        ub_f, ub_r, L_sp);
    em_gemm_xpT<<<dim3(NT64, 2, 2), 256, 0, stream>>>(
        ub_f, ub_r, spxp_bf + (size_t)i * XDIM * EDIM, spxpr_bf + (size_t)i * XDIM * EDIM,
        dblT_f, dblT_r);
    em_dtproj<<<dim3(EDIM / 256, NT16, 2), 256, 0, stream>>>(
        dblT_f, dblT_r, sp_dtw + (size_t)i * EDIM * RDIM, sp_dtw_r + (size_t)i * EDIM * RDIM,
        sp_dtb + (size_t)i * EDIM, sp_dtb_r + (size_t)i * EDIM, dt_f, dt_r);
    if (spCL == 16)
      em_scan_sum<16><<<dim3(EDIM / 256, 16 * NC_sp, 2), 256, 0, stream>>>(
          dt_f, dt_r, ub_f, ub_r, dblT_f, dblT_r, Alf, Alr,
          scanP_f, scanP_r, scanH_f, scanH_r, L_sp, NC_sp);
    else
      em_scan_sum<32><<<dim3(EDIM / 256, 16 * NC_sp, 2), 256, 0, stream>>>(
          dt_f, dt_r, ub_f, ub_r, dblT_f, dblT_r, Alf, Alr,
          scanP_f, scanP_r, scanH_f, scanH_r, L_sp, NC_sp);
    em_scan_combine<<<dim3(16 * EDIM * SDIM / 256, 1, 2), 256, 0, stream>>>(
        scanP_f, scanP_r, scanH_f, scanH_r, NC_sp);
    if (spCL == 16)
      em_scan_out<16><<<dim3(EDIM / 256, 16 * NC_sp, 2), 256, 0, stream>>>(
          dt_f, dt_r, ub_f, ub_r, dblT_f, dblT_r, xz, Alf, Alr,
          sp_D + (size_t)i * EDIM, sp_D_r + (size_t)i * EDIM,
          scanH_f, scanH_r, yb_f, yb_r, L_sp, NC_sp);
    else
      em_scan_out<32><<<dim3(EDIM / 256, 16 * NC_sp, 2), 256, 0, stream>>>(
          dt_f, dt_r, ub_f, ub_r, dblT_f, dblT_r, xz, Alf, Alr,
          sp_D + (size_t)i * EDIM, sp_D_r + (size_t)i * EDIM,
          scanH_f, scanH_r, yb_f, yb_r, L_sp, NC_sp);
    em_gemm_abf<<<dim3(DMODEL / TN, MT, 2), 256, 0, stream>>>(
        yb_f, yb_r, spout_bf + (size_t)i * DMODEL * EDIM, hidden, NTOKS, DMODEL, EDIM / 2, EDIM);
    const float* next_w = (i < NLAYER - 1) ? sp_norm + (size_t)(i + 1) * DMODEL : tm_norm;
    em_add_rmsnorm<<<NTOKS, DMODEL, 0, stream>>>(hidden, hidden2, residual, residual,
                                                 next_w, nullptr, xn_bf);
  }

  // -------- 12 temporal mamba blocks: N=2 sequences of L=1576 --------
  for (int i = 0; i < NLAYER; ++i) {
    const float* Al = tm_Alog + (size_t)i * EDIM * SDIM;
    em_gemm_abf<<<dim3(TWOE / TN, MT, 1), 256, 0, stream>>>(
        xn_bf, nullptr, tmin_bf + (size_t)i * TWOE * DMODEL, xz, NTOKS, TWOE, DMODEL, DMODEL);
    em_conv_silu<<<dim3(EDIM / 256, NTC, 1), 256, 0, stream>>>(
        xz, tm_conv_w + (size_t)i * EDIM * 4, tm_conv_b + (size_t)i * EDIM,
        tm_conv_w + (size_t)i * EDIM * 4, tm_conv_b + (size_t)i * EDIM,
        ub_f, ub_r, L_tm);
    em_gemm_xpT<<<dim3(NT64, 2, 1), 256, 0, stream>>>(
        ub_f, ub_r, tmxp_bf + (size_t)i * XDIM * EDIM, tmxp_bf + (size_t)i * XDIM * EDIM,
        dblT_f, dblT_r);
    em_dtproj<<<dim3(EDIM / 256, NT16, 1), 256, 0, stream>>>(
        dblT_f, dblT_r, tm_dtw + (size_t)i * EDIM * RDIM, tm_dtw + (size_t)i * EDIM * RDIM,
        tm_dtb + (size_t)i * EDIM, tm_dtb + (size_t)i * EDIM, dt_f, dt_r);
    if (tmCL == 8)
      em_scan_sum<8><<<dim3(EDIM / 256, 2 * NC_tm, 1), 256, 0, stream>>>(
          dt_f, dt_r, ub_f, ub_r, dblT_f, dblT_r, Al, Al,
          scanP_f, scanP_r, scanH_f, scanH_r, L_tm, NC_tm);
    else
      em_scan_sum<16><<<dim3(EDIM / 256, 2 * NC_tm, 1), 256, 0, stream>>>(
          dt_f, dt_r, ub_f, ub_r, dblT_f, dblT_r, Al, Al,
          scanP_f, scanP_r, scanH_f, scanH_r, L_tm, NC_tm);
    em_scan_combine<<<dim3(2 * EDIM * SDIM / 256, 1, 1), 256, 0, stream>>>(
        scanP_f, scanP_r, scanH_f, scanH_r, NC_tm);
    if (tmCL == 8)
      em_scan_out<8><<<dim3(EDIM / 256, 2 * NC_tm, 1), 256, 0, stream>>>(
          dt_f, dt_r, ub_f, ub_r, dblT_f, dblT_r, xz, Al, Al,
          tm_D + (size_t)i * EDIM, tm_D + (size_t)i * EDIM,
          scanH_f, scanH_r, yb_f, yb_r, L_tm, NC_tm);
    else
      em_scan_out<16><<<dim3(EDIM / 256, 2 * NC_tm, 1), 256, 0, stream>>>(
          dt_f, dt_r, ub_f, ub_r, dblT_f, dblT_r, xz, Al, Al,
          tm_D + (size_t)i * EDIM, tm_D + (size_t)i * EDIM,
          scanH_f, scanH_r, yb_f, yb_r, L_tm, NC_tm);
    em_gemm_abf<<<dim3(DMODEL / TN, MT, 2), 256, 0, stream>>>(
        yb_f, nullptr, tmout_bf + (size_t)i * DMODEL * EDIM, hidden, NTOKS, DMODEL, EDIM / 2, EDIM);
    const bool last = (i == NLAYER - 1);
    const float* next_w = last ? normf : tm_norm + (size_t)(i + 1) * DMODEL;
    em_add_rmsnorm<<<NTOKS, DMODEL, 0, stream>>>(hidden, hidden2, residual,
                                                 last ? nullptr : residual,
                                                 next_w, last ? (float*)d_out : nullptr,
                                                 last ? nullptr : xn_bf);
  }
}